// Round 1
// baseline (2592.976 us; speedup 1.0000x reference)
//
#include <hip/hip_runtime.h>
#include <stdint.h>

typedef __attribute__((ext_vector_type(8))) short bf16x8v;
typedef __attribute__((ext_vector_type(4))) float f32x4v;

#define DEV static __device__ __forceinline__

#define B_   64
#define TC_  637
#define TCP_ 638
#define TT_  24
#define E_   300
#define KP_  320
#define H_   256
#define NG_  2048

DEV uint16_t f2bf(float f) {
    uint32_t u = __float_as_uint(f);
    u += 0x7fffu + ((u >> 16) & 1u);
    return (uint16_t)(u >> 16);
}
DEV float bf2f(uint16_t h) { return __uint_as_float(((uint32_t)h) << 16); }
DEV float sigm(float x)  { return __builtin_amdgcn_rcpf(1.f + __expf(-x)); }
DEV float tanhx(float x) { return 1.f - 2.f*__builtin_amdgcn_rcpf(1.f + __expf(2.f*x)); }

// ---------------- weight prep: fp32 -> bf16 (+ K-pad), bias concat ----------
__global__ void k_prep(const float* t_wih_f, const float* t_wih_b,
                       const float* t_whh_f,
                       const float* c_wih_f, const float* c_wih_b,
                       const float* c_whh_f, const float* c_whh_b,
                       const float* t_b_f, const float* t_b_b,
                       const float* c_b_f, const float* c_b_b,
                       uint16_t* BwC, uint16_t* BwT, float* biasC, float* biasT,
                       uint16_t* whhCF, uint16_t* whhCB, uint16_t* whhTF)
{
    int tid = blockIdx.x*blockDim.x + threadIdx.x;
    int nth = gridDim.x*blockDim.x;
    for (int i = tid; i < NG_*KP_; i += nth) {
        int n = i / KP_, k = i - n*KP_;
        float vc = 0.f, vt = 0.f;
        if (k < E_) {
            vc = (n < 1024) ? c_wih_f[n*E_+k] : c_wih_b[(n-1024)*E_+k];
            vt = (n < 1024) ? t_wih_f[n*E_+k] : t_wih_b[(n-1024)*E_+k];
        }
        BwC[i] = f2bf(vc); BwT[i] = f2bf(vt);
    }
    for (int i = tid; i < 1024*H_; i += nth) {
        whhCF[i] = f2bf(c_whh_f[i]);
        whhCB[i] = f2bf(c_whh_b[i]);
        whhTF[i] = f2bf(t_whh_f[i]);
    }
    for (int i = tid; i < NG_; i += nth) {
        biasC[i] = (i < 1024) ? c_b_f[i] : c_b_b[i-1024];
        biasT[i] = (i < 1024) ? t_b_f[i] : t_b_b[i-1024];
    }
}

// ---------------- embedding gather -> bf16 A matrices (row m = t*64 + b) ----
__global__ void k_gather(const int* __restrict__ content, const int* __restrict__ title,
                         const float* __restrict__ emb,
                         uint16_t* __restrict__ Ac, uint16_t* __restrict__ At)
{
    int tid = blockIdx.x*blockDim.x + threadIdx.x;
    int nth = gridDim.x*blockDim.x;
    const int CCH = 40832*40;
    const int TCH = 1536*40;
    for (int i = tid; i < CCH + TCH; i += nth) {
        uint16_t* dst; int row, c8; int tok;
        if (i < CCH) {
            row = i / 40; c8 = i - row*40;
            int t = row >> 6, b = row & 63;
            tok = (t < TC_) ? content[b*TC_ + t] : -1;
            dst = Ac + (size_t)row*KP_ + c8*8;
        } else {
            int jx = i - CCH;
            row = jx / 40; c8 = jx - row*40;
            int t = row >> 6, b = row & 63;
            tok = title[b*TT_ + t];
            dst = At + (size_t)row*KP_ + c8*8;
        }
        uint32_t dd[4];
        #pragma unroll
        for (int p = 0; p < 4; ++p) {
            int k = c8*8 + p*2;
            float f0 = (tok >= 0 && k   < E_) ? emb[(size_t)tok*E_ + k]   : 0.f;
            float f1 = (tok >= 0 && k+1 < E_) ? emb[(size_t)tok*E_ + k+1] : 0.f;
            dd[p] = (uint32_t)f2bf(f0) | ((uint32_t)f2bf(f1) << 16);
        }
        uint4 q; q.x = dd[0]; q.y = dd[1]; q.z = dd[2]; q.w = dd[3];
        *(uint4*)dst = q;
    }
}

// ---------------- pre-GEMM: C[m][n] = sum_k A[m][k]*Bw[n][k] + bias[n] ------
// 128x128 tile, BK=32, 4 waves, double-buffered reg-staged LDS.
// Epilogue stores bf16 into MFMA-fragment-permuted layout consumed by k_rnn.
__global__ __launch_bounds__(256) void k_gemm(const uint16_t* __restrict__ A,
        const uint16_t* __restrict__ Bw, const float* __restrict__ bias,
        uint16_t* __restrict__ prep)
{
    __shared__ uint16_t lA[2][128*32];
    __shared__ uint16_t lB[2][128*32];
    const int tid = threadIdx.x;
    const int l = tid & 63, wv = tid >> 6;
    const int m0 = blockIdx.y * 128, n0 = blockIdx.x * 128;

    uint4 rA[2], rB[2];
    auto issue = [&](int kc) {
        #pragma unroll
        for (int r = 0; r < 2; ++r) {
            int row = r*64 + (tid >> 2);
            int cu  = (tid & 3) * 8;
            rA[r] = *(const uint4*)(A  + (size_t)(m0 + row)*KP_ + kc*32 + cu);
            rB[r] = *(const uint4*)(Bw + (size_t)(n0 + row)*KP_ + kc*32 + cu);
        }
    };
    auto writeb = [&](int bi) {
        #pragma unroll
        for (int r = 0; r < 2; ++r) {
            *(uint4*)&lA[bi][r*2048 + tid*8] = rA[r];
            *(uint4*)&lB[bi][r*2048 + tid*8] = rB[r];
        }
    };

    f32x4v acc[4][4];
    #pragma unroll
    for (int i = 0; i < 4; ++i)
        #pragma unroll
        for (int j = 0; j < 4; ++j)
            acc[i][j] = f32x4v{0.f,0.f,0.f,0.f};

    const int mtb = (wv >> 1) * 4, ntb = (wv & 1) * 4;

    issue(0); writeb(0); __syncthreads();
    for (int kc = 0; kc < 10; ++kc) {
        if (kc < 9) issue(kc + 1);
        {   // compute current buffer
            int bi = kc & 1;
            bf16x8v af[4], bfr[4];
            #pragma unroll
            for (int i = 0; i < 4; ++i) {
                af[i]  = *(const bf16x8v*)&lA[bi][((mtb+i)*16 + (l&15))*32 + (l>>4)*8];
                bfr[i] = *(const bf16x8v*)&lB[bi][((ntb+i)*16 + (l&15))*32 + (l>>4)*8];
            }
            #pragma unroll
            for (int i = 0; i < 4; ++i)
                #pragma unroll
                for (int j = 0; j < 4; ++j)
                    acc[i][j] = __builtin_amdgcn_mfma_f32_16x16x32_bf16(af[i], bfr[j], acc[i][j], 0,0,0);
        }
        if (kc < 9) writeb((kc + 1) & 1);
        __syncthreads();
    }

    // epilogue: bias + bf16 + fragment-permuted store
    #pragma unroll
    for (int j = 0; j < 4; ++j) {
        int nt = ntb + j;
        int n  = n0 + nt*16;
        int dir  = n >> 10;
        int nj   = n & 1023;
        int type = nj >> 8;
        int w    = (nj >> 5) & 7;
        int jt   = (nj >> 4) & 1;
        int tau  = type*2 + jt;
        float bv = bias[n + (l & 15)];
        #pragma unroll
        for (int i = 0; i < 4; ++i) {
            int mt   = mtb + i;
            int row0 = mt*16 + (l >> 4)*4;
            int t    = (m0 + row0) >> 6;
            int bblk = mt & 3;
            ushort4 pk;
            pk.x = f2bf(acc[i][j][0] + bv);
            pk.y = f2bf(acc[i][j][1] + bv);
            pk.z = f2bf(acc[i][j][2] + bv);
            pk.w = f2bf(acc[i][j][3] + bv);
            size_t off = ((((size_t)t*4 + bblk)*2 + dir)*8 + w)*2048 + (size_t)l*32 + tau*4;
            *(ushort4*)(prep + off) = pk;
        }
    }
}

// ---------------- recurrence: one block per (direction, 16-batch) unit ------
// 8 waves; whh resident: 6 n-tiles in 192 VGPRs + 2 n-tiles in 128KB LDS.
// h exchanged via 8KB swizzled LDS buffer; 2 barriers/step; no global sync.
__global__ __launch_bounds__(512, 2) void k_rnn(
    const uint16_t* __restrict__ preC, const uint16_t* __restrict__ preT,
    const uint16_t* __restrict__ whhCF, const uint16_t* __restrict__ whhCB,
    const uint16_t* __restrict__ whhTF,
    uint16_t* __restrict__ cr, float* __restrict__ tl)
{
    __shared__ uint16_t smem[69632];   // [0,4096): h (8KB)  [4096,69632): weights (128KB)
    uint16_t* hlds = smem;
    uint16_t* ldsW = smem + 4096;

    const int tid = threadIdx.x;
    const int l = tid & 63, w = tid >> 6;
    const int u = blockIdx.x;

    int dir, bblk, t0, tstep, nsteps, tlOff = -1;
    bool doCR = false;
    const uint16_t* pre; const uint16_t* whh = nullptr;
    if (u < 8) {
        dir = u & 1; bblk = u >> 1;
        nsteps = TC_; t0 = dir ? (TC_-1) : 0; tstep = dir ? -1 : 1;
        whh = dir ? whhCB : whhCF; pre = preC; doCR = true;
    } else if (u < 12) {
        dir = 0; bblk = u - 8; nsteps = TT_; t0 = 0; tstep = 1;
        whh = whhTF; pre = preT; tlOff = 0;
    } else {
        dir = 1; bblk = u - 12; nsteps = 1; t0 = TT_-1; tstep = -1;
        whh = nullptr; pre = preT; tlOff = 256;
    }
    const int b0 = bblk * 16;

    bf16x8v wreg[6][8];
    if (whh) {
        #pragma unroll
        for (int tau = 0; tau < 6; ++tau) {
            int n = (tau >> 1)*256 + w*32 + (tau & 1)*16 + (l & 15);
            #pragma unroll
            for (int kc = 0; kc < 8; ++kc)
                wreg[tau][kc] = *(const bf16x8v*)(whh + (size_t)n*H_ + kc*32 + (l>>4)*8);
        }
        #pragma unroll
        for (int ti = 0; ti < 2; ++ti) {
            int n = 3*256 + w*32 + ti*16 + (l & 15);     // tau = 6,7  (o-gates)
            #pragma unroll
            for (int kc = 0; kc < 8; ++kc) {
                uint4 v = *(const uint4*)(whh + (size_t)n*H_ + kc*32 + (l>>4)*8);
                *(uint4*)&ldsW[w*8192 + (ti*8 + kc)*512 + l*8] = v;
            }
        }
    }
    for (int i = tid; i < 4096; i += 512) hlds[i] = 0;
    __syncthreads();

    float cst[2][4];
    #pragma unroll
    for (int jt = 0; jt < 2; ++jt)
        #pragma unroll
        for (int r = 0; r < 4; ++r) cst[jt][r] = 0.f;

    for (int s = 0; s < nsteps; ++s) {
        int t = t0 + s*tstep;
        const uint16_t* pp = pre + ((((size_t)t*4 + bblk)*2 + dir)*8 + w)*2048 + (size_t)l*32;
        f32x4v acc[8];
        #pragma unroll
        for (int tau = 0; tau < 8; ++tau) {
            uint2 d = *(const uint2*)(pp + tau*4);
            acc[tau][0] = bf2f((uint16_t)(d.x & 0xffff));
            acc[tau][1] = bf2f((uint16_t)(d.x >> 16));
            acc[tau][2] = bf2f((uint16_t)(d.y & 0xffff));
            acc[tau][3] = bf2f((uint16_t)(d.y >> 16));
        }
        if (whh) {
            #pragma unroll
            for (int kc = 0; kc < 8; ++kc) {
                int abyte = ((l & 15)*512 + kc*64 + (l >> 4)*16) ^ ((l & 7) << 4);
                bf16x8v a = *(const bf16x8v*)((const char*)hlds + abyte);
                #pragma unroll
                for (int tau = 0; tau < 6; ++tau)
                    acc[tau] = __builtin_amdgcn_mfma_f32_16x16x32_bf16(a, wreg[tau][kc], acc[tau], 0,0,0);
                bf16x8v w6 = *(const bf16x8v*)&ldsW[w*8192 + kc*512 + l*8];
                bf16x8v w7 = *(const bf16x8v*)&ldsW[w*8192 + (8+kc)*512 + l*8];
                acc[6] = __builtin_amdgcn_mfma_f32_16x16x32_bf16(a, w6, acc[6], 0,0,0);
                acc[7] = __builtin_amdgcn_mfma_f32_16x16x32_bf16(a, w7, acc[7], 0,0,0);
            }
        }
        __syncthreads();   // all reads of h_{t-1} done before overwrite

        #pragma unroll
        for (int jt = 0; jt < 2; ++jt) {
            #pragma unroll
            for (int r = 0; r < 4; ++r) {
                float iv = acc[0+jt][r], fv = acc[2+jt][r];
                float gv = acc[4+jt][r], ov = acc[6+jt][r];
                float si = sigm(iv), sf = sigm(fv), so = sigm(ov);
                float tg = tanhx(gv);
                float cv = sf*cst[jt][r] + si*tg;
                cst[jt][r] = cv;
                float hv = so * tanhx(cv);
                uint16_t hb = f2bf(hv);
                int m = (l >> 4)*4 + r;
                int j = w*32 + jt*16 + (l & 15);
                int byte = (m*512 + j*2) ^ ((m & 7) << 4);
                *(uint16_t*)((char*)hlds + byte) = hb;
                if (doCR)
                    cr[((size_t)(b0 + m)*TC_ + t)*512 + dir*256 + j] = hb;
                if (tlOff >= 0 && s == nsteps-1)
                    tl[(size_t)(b0 + m)*512 + tlOff + j] = hv;
            }
        }
        __syncthreads();   // h_t visible to all waves
    }
}

// ---------------- attention + fc + log_softmax, one block per batch --------
__global__ __launch_bounds__(256) void k_attn(const uint16_t* __restrict__ cr,
        const float* __restrict__ tl, const float* __restrict__ attw,
        const float* __restrict__ fcw, const float* __restrict__ fcb,
        float* __restrict__ out)
{
    __shared__ float sT[512];
    __shared__ float sQ[512];
    __shared__ float sS[640];
    __shared__ float sR[256];
    const int b = blockIdx.x, tid = threadIdx.x;
    for (int i = tid; i < 512; i += 256) sT[i] = tl[(size_t)b*512 + i];
    __syncthreads();
    for (int n = tid; n < 512; n += 256) {
        float s = 0.f;
        for (int j = 0; j < 512; ++j) s += sT[j] * attw[(size_t)j*512 + n];
        sQ[n] = s;
    }
    __syncthreads();
    for (int t = tid; t < TC_; t += 256) {
        const uint16_t* row = cr + ((size_t)b*TC_ + t)*512;
        float s = 0.f;
        for (int c = 0; c < 64; ++c) {
            uint4 v = *(const uint4*)(row + c*8);
            uint32_t d;
            d = v.x; s += bf2f((uint16_t)(d&0xffff))*sQ[c*8+0] + bf2f((uint16_t)(d>>16))*sQ[c*8+1];
            d = v.y; s += bf2f((uint16_t)(d&0xffff))*sQ[c*8+2] + bf2f((uint16_t)(d>>16))*sQ[c*8+3];
            d = v.z; s += bf2f((uint16_t)(d&0xffff))*sQ[c*8+4] + bf2f((uint16_t)(d>>16))*sQ[c*8+5];
            d = v.w; s += bf2f((uint16_t)(d&0xffff))*sQ[c*8+6] + bf2f((uint16_t)(d>>16))*sQ[c*8+7];
        }
        sS[t] = s;
    }
    __syncthreads();
    float lm = -1e30f;
    for (int t = tid; t < TC_; t += 256) lm = fmaxf(lm, sS[t]);
    sR[tid] = lm; __syncthreads();
    for (int o = 128; o > 0; o >>= 1) { if (tid < o) sR[tid] = fmaxf(sR[tid], sR[tid+o]); __syncthreads(); }
    float M = sR[0]; __syncthreads();
    float ls = 0.f;
    for (int t = tid; t < TC_; t += 256) { float e = __expf(sS[t]-M); sS[t] = e; ls += e; }
    sR[tid] = ls; __syncthreads();
    for (int o = 128; o > 0; o >>= 1) { if (tid < o) sR[tid] += sR[tid+o]; __syncthreads(); }
    float inv = 1.f / sR[0]; __syncthreads();
    float la[5] = {0.f,0.f,0.f,0.f,0.f};
    for (int t = tid; t < TC_; t += 256) {
        float p = sS[t] * inv;
        #pragma unroll
        for (int ll = 0; ll < 5; ++ll) la[ll] += p * fcw[ll*TC_ + t];
    }
    float lg[5];
    #pragma unroll
    for (int ll = 0; ll < 5; ++ll) {
        sR[tid] = la[ll]; __syncthreads();
        for (int o = 128; o > 0; o >>= 1) { if (tid < o) sR[tid] += sR[tid+o]; __syncthreads(); }
        lg[ll] = sR[0] + fcb[ll]; __syncthreads();
    }
    if (tid == 0) {
        float m2 = lg[0];
        #pragma unroll
        for (int ll = 1; ll < 5; ++ll) m2 = fmaxf(m2, lg[ll]);
        float se = 0.f;
        #pragma unroll
        for (int ll = 0; ll < 5; ++ll) se += __expf(lg[ll] - m2);
        float lse = __logf(se) + m2;
        #pragma unroll
        for (int ll = 0; ll < 5; ++ll) out[b*5 + ll] = lg[ll] - lse;
    }
}

// ---------------------------------------------------------------------------
extern "C" void kernel_launch(void* const* d_in, const int* in_sizes, int n_in,
                              void* d_out, int out_size, void* d_ws, size_t ws_size,
                              hipStream_t stream)
{
    const int*   content = (const int*)d_in[0];
    const int*   title   = (const int*)d_in[1];
    const float* embed_w = (const float*)d_in[2];
    const float* t_wih_f = (const float*)d_in[3];
    const float* t_whh_f = (const float*)d_in[4];
    const float* t_b_f   = (const float*)d_in[5];
    const float* t_wih_b = (const float*)d_in[6];
    const float* t_b_b   = (const float*)d_in[8];
    const float* c_wih_f = (const float*)d_in[9];
    const float* c_whh_f = (const float*)d_in[10];
    const float* c_b_f   = (const float*)d_in[11];
    const float* c_wih_b = (const float*)d_in[12];
    const float* c_whh_b = (const float*)d_in[13];
    const float* c_b_b   = (const float*)d_in[14];
    const float* att_w   = (const float*)d_in[15];
    const float* fc_w    = (const float*)d_in[16];
    const float* fc_b    = (const float*)d_in[17];
    float* out = (float*)d_out;

    char* ws = (char*)d_ws;
    size_t o = 0;
    auto alloc = [&](size_t sz) { char* p = ws + o; o = (o + sz + 255) & ~(size_t)255; return p; };
    uint16_t* Ac    = (uint16_t*)alloc((size_t)40832*KP_*2);
    uint16_t* At    = (uint16_t*)alloc((size_t)1536*KP_*2);
    uint16_t* BwC   = (uint16_t*)alloc((size_t)NG_*KP_*2);
    uint16_t* BwT   = (uint16_t*)alloc((size_t)NG_*KP_*2);
    float*    biasC = (float*)   alloc((size_t)NG_*4);
    float*    biasT = (float*)   alloc((size_t)NG_*4);
    uint16_t* whhCF = (uint16_t*)alloc((size_t)1024*H_*2);
    uint16_t* whhCB = (uint16_t*)alloc((size_t)1024*H_*2);
    uint16_t* whhTF = (uint16_t*)alloc((size_t)1024*H_*2);
    uint16_t* preC  = (uint16_t*)alloc((size_t)TCP_*262144);
    uint16_t* preT  = (uint16_t*)alloc((size_t)TT_*262144);
    uint16_t* crp   = (uint16_t*)alloc((size_t)B_*TC_*512*2);
    float*    tlp   = (float*)   alloc((size_t)B_*512*4);

    k_prep<<<256, 256, 0, stream>>>(t_wih_f, t_wih_b, t_whh_f, c_wih_f, c_wih_b,
                                    c_whh_f, c_whh_b, t_b_f, t_b_b, c_b_f, c_b_b,
                                    BwC, BwT, biasC, biasT, whhCF, whhCB, whhTF);
    k_gather<<<2048, 256, 0, stream>>>(content, title, embed_w, Ac, At);
    k_gemm<<<dim3(16, 319), 256, 0, stream>>>(Ac, BwC, biasC, preC);
    k_gemm<<<dim3(16, 12),  256, 0, stream>>>(At, BwT, biasT, preT);
    k_rnn<<<16, 512, 0, stream>>>(preC, preT, whhCF, whhCB, whhTF, crp, tlp);
    k_attn<<<64, 256, 0, stream>>>(crp, tlp, att_w, fc_w, fc_b, out);
}

// Round 2
// 2248.960 us; speedup vs baseline: 1.1530x; 1.1530x over previous
//
#include <hip/hip_runtime.h>
#include <stdint.h>

typedef __attribute__((ext_vector_type(8))) short bf16x8v;
typedef __attribute__((ext_vector_type(4))) float f32x4v;
typedef long long i64;

#define DEV static __device__ __forceinline__

#define B_   64
#define TC_  637
#define TCP_ 638
#define TT_  24
#define E_   300
#define KP_  320
#define H_   256
#define NG_  2048

DEV uint16_t f2bf(float f) {
    uint32_t u = __float_as_uint(f);
    u += 0x7fffu + ((u >> 16) & 1u);
    return (uint16_t)(u >> 16);
}
DEV float bf2f(uint16_t h) { return __uint_as_float(((uint32_t)h) << 16); }
DEV float sigm(float x)  { return __builtin_amdgcn_rcpf(1.f + __expf(-x)); }
DEV float tanhx(float x) { return 1.f - 2.f*__builtin_amdgcn_rcpf(1.f + __expf(2.f*x)); }

DEV void gload_lds16(const void* g, void* l) {
    __builtin_amdgcn_global_load_lds((const __attribute__((address_space(1))) uint32_t*)g,
                                     (__attribute__((address_space(3))) uint32_t*)l, 16, 0, 0);
}

// ---------------- weight prep: fp32 -> bf16 / fp8 (+ K-pad), bias concat ----
__global__ void k_prep(const float* t_wih_f, const float* t_wih_b,
                       const float* t_whh_f,
                       const float* c_wih_f, const float* c_wih_b,
                       const float* c_whh_f, const float* c_whh_b,
                       const float* t_b_f, const float* t_b_b,
                       const float* c_b_f, const float* c_b_b,
                       uint16_t* BwC, uint16_t* BwT, float* biasC, float* biasT,
                       uint16_t* whhCF, uint16_t* whhCB, uint16_t* whhTF,
                       uint32_t* w8CF, uint32_t* w8CB, uint32_t* w8TF)
{
    int tid = blockIdx.x*blockDim.x + threadIdx.x;
    int nth = gridDim.x*blockDim.x;
    for (int i = tid; i < NG_*KP_; i += nth) {
        int n = i / KP_, k = i - n*KP_;
        float vc = 0.f, vt = 0.f;
        if (k < E_) {
            vc = (n < 1024) ? c_wih_f[n*E_+k] : c_wih_b[(n-1024)*E_+k];
            vt = (n < 1024) ? t_wih_f[n*E_+k] : t_wih_b[(n-1024)*E_+k];
        }
        BwC[i] = f2bf(vc); BwT[i] = f2bf(vt);
    }
    for (int i = tid; i < 1024*H_; i += nth) {      // bf16 whh (g-gate fragments)
        whhCF[i] = f2bf(c_whh_f[i]);
        whhCB[i] = f2bf(c_whh_b[i]);
        whhTF[i] = f2bf(t_whh_f[i]);
    }
    for (int i = tid; i < 1024*H_/4; i += nth) {    // fp8 whh (i,f,o fragments)
        int base = i*4;
        uint32_t a, b, c;
        a = (uint32_t)__builtin_amdgcn_cvt_pk_fp8_f32(c_whh_f[base], c_whh_f[base+1], 0, false);
        a = (uint32_t)__builtin_amdgcn_cvt_pk_fp8_f32(c_whh_f[base+2], c_whh_f[base+3], (int)a, true);
        b = (uint32_t)__builtin_amdgcn_cvt_pk_fp8_f32(c_whh_b[base], c_whh_b[base+1], 0, false);
        b = (uint32_t)__builtin_amdgcn_cvt_pk_fp8_f32(c_whh_b[base+2], c_whh_b[base+3], (int)b, true);
        c = (uint32_t)__builtin_amdgcn_cvt_pk_fp8_f32(t_whh_f[base], t_whh_f[base+1], 0, false);
        c = (uint32_t)__builtin_amdgcn_cvt_pk_fp8_f32(t_whh_f[base+2], t_whh_f[base+3], (int)c, true);
        w8CF[i] = a; w8CB[i] = b; w8TF[i] = c;
    }
    for (int i = tid; i < NG_; i += nth) {
        biasC[i] = (i < 1024) ? c_b_f[i] : c_b_b[i-1024];
        biasT[i] = (i < 1024) ? t_b_f[i] : t_b_b[i-1024];
    }
}

// ---------------- embedding gather -> bf16 A matrices (row m = t*64 + b) ----
__global__ void k_gather(const int* __restrict__ content, const int* __restrict__ title,
                         const float* __restrict__ emb,
                         uint16_t* __restrict__ Ac, uint16_t* __restrict__ At)
{
    int tid = blockIdx.x*blockDim.x + threadIdx.x;
    int nth = gridDim.x*blockDim.x;
    const int CCH = 40832*40;
    const int TCH = 1536*40;
    for (int i = tid; i < CCH + TCH; i += nth) {
        uint16_t* dst; int row, c8; int tok;
        if (i < CCH) {
            row = i / 40; c8 = i - row*40;
            int t = row >> 6, b = row & 63;
            tok = (t < TC_) ? content[b*TC_ + t] : -1;
            dst = Ac + (size_t)row*KP_ + c8*8;
        } else {
            int jx = i - CCH;
            row = jx / 40; c8 = jx - row*40;
            int t = row >> 6, b = row & 63;
            tok = title[b*TT_ + t];
            dst = At + (size_t)row*KP_ + c8*8;
        }
        uint32_t dd[4];
        #pragma unroll
        for (int p = 0; p < 4; ++p) {
            int k = c8*8 + p*2;
            float f0 = (tok >= 0 && k   < E_) ? emb[(size_t)tok*E_ + k]   : 0.f;
            float f1 = (tok >= 0 && k+1 < E_) ? emb[(size_t)tok*E_ + k+1] : 0.f;
            dd[p] = (uint32_t)f2bf(f0) | ((uint32_t)f2bf(f1) << 16);
        }
        uint4 q; q.x = dd[0]; q.y = dd[1]; q.z = dd[2]; q.w = dd[3];
        *(uint4*)dst = q;
    }
}

// ---------------- pre-GEMM: C[m][n] = sum_k A[m][k]*Bw[n][k] + bias[n] ------
// 128x128 tile, BK=32, 4 waves, double-buffered global_load_lds staging.
__global__ __launch_bounds__(256) void k_gemm(const uint16_t* __restrict__ A,
        const uint16_t* __restrict__ Bw, const float* __restrict__ bias,
        uint16_t* __restrict__ prep)
{
    __shared__ __align__(16) uint16_t lA[2][128*32];
    __shared__ __align__(16) uint16_t lB[2][128*32];
    const int tid = threadIdx.x;
    const int l = tid & 63, wv = tid >> 6;
    const int m0 = blockIdx.y * 128, n0 = blockIdx.x * 128;

    auto stage = [&](int kc, int bi) {
        #pragma unroll
        for (int r = 0; r < 2; ++r) {
            int row = r*64 + (tid >> 2);
            int cu  = (tid & 3) * 8;
            gload_lds16(A  + (size_t)(m0 + row)*KP_ + kc*32 + cu, &lA[bi][r*2048 + wv*512]);
            gload_lds16(Bw + (size_t)(n0 + row)*KP_ + kc*32 + cu, &lB[bi][r*2048 + wv*512]);
        }
    };

    f32x4v acc[4][4];
    #pragma unroll
    for (int i = 0; i < 4; ++i)
        #pragma unroll
        for (int j = 0; j < 4; ++j)
            acc[i][j] = f32x4v{0.f,0.f,0.f,0.f};

    const int mtb = (wv >> 1) * 4, ntb = (wv & 1) * 4;

    stage(0, 0);
    __syncthreads();
    for (int kc = 0; kc < 10; ++kc) {
        if (kc < 9) stage(kc + 1, (kc + 1) & 1);
        {
            int bi = kc & 1;
            bf16x8v af[4], bfr[4];
            #pragma unroll
            for (int i = 0; i < 4; ++i) {
                af[i]  = *(const bf16x8v*)&lA[bi][((mtb+i)*16 + (l&15))*32 + (l>>4)*8];
                bfr[i] = *(const bf16x8v*)&lB[bi][((ntb+i)*16 + (l&15))*32 + (l>>4)*8];
            }
            #pragma unroll
            for (int i = 0; i < 4; ++i)
                #pragma unroll
                for (int j = 0; j < 4; ++j)
                    acc[i][j] = __builtin_amdgcn_mfma_f32_16x16x32_bf16(af[i], bfr[j], acc[i][j], 0,0,0);
        }
        __syncthreads();   // drains DMA for next buf + protects overwrite
    }

    // epilogue: bias + bf16 + fragment-permuted store (consumed by k_rnn)
    #pragma unroll
    for (int j = 0; j < 4; ++j) {
        int nt = ntb + j;
        int n  = n0 + nt*16;
        int dir  = n >> 10;
        int nj   = n & 1023;
        int type = nj >> 8;
        int w    = (nj >> 5) & 7;
        int jt   = (nj >> 4) & 1;
        int tau  = type*2 + jt;
        float bv = bias[n + (l & 15)];
        #pragma unroll
        for (int i = 0; i < 4; ++i) {
            int mt   = mtb + i;
            int row0 = mt*16 + (l >> 4)*4;
            int t    = (m0 + row0) >> 6;
            int bblk = mt & 3;
            ushort4 pk;
            pk.x = f2bf(acc[i][j][0] + bv);
            pk.y = f2bf(acc[i][j][1] + bv);
            pk.z = f2bf(acc[i][j][2] + bv);
            pk.w = f2bf(acc[i][j][3] + bv);
            size_t off = ((((size_t)t*4 + bblk)*2 + dir)*8 + w)*2048 + (size_t)l*32 + tau*4;
            *(ushort4*)(prep + off) = pk;
        }
    }
}

// ---------------- recurrence: one block per (direction, 16-batch) unit ------
// 8 waves. ALL whh register-resident: i/f/o as fp8 (96 VGPR) + g as bf16
// (64 VGPR). LDS = dual-format h, double-buffered (24KB). One raw barrier
// per step (lgkmcnt only -- cr stores & pre prefetch stay in flight).
__global__ __launch_bounds__(512, 2) void k_rnn(
    const uint16_t* __restrict__ preC, const uint16_t* __restrict__ preT,
    const uint16_t* __restrict__ whhCF, const uint16_t* __restrict__ whhCB,
    const uint16_t* __restrict__ whhTF,
    const uint8_t* __restrict__ w8CF, const uint8_t* __restrict__ w8CB,
    const uint8_t* __restrict__ w8TF,
    uint16_t* __restrict__ cr, float* __restrict__ tl)
{
    // per buffer: 8192B bf16-h + 4096B fp8-h = 12288B; two buffers = 24KB
    __shared__ __align__(16) char smem[24576];

    const int tid = threadIdx.x;
    const int l = tid & 63, w = tid >> 6;
    const int u = blockIdx.x;

    int dir, bblk, t0, tstep, nsteps, tlOff = -1;
    bool doCR = false;
    const uint16_t* pre; const uint16_t* whh = nullptr; const uint8_t* whh8 = nullptr;
    if (u < 8) {
        dir = u & 1; bblk = u >> 1;
        nsteps = TC_; t0 = dir ? (TC_-1) : 0; tstep = dir ? -1 : 1;
        whh = dir ? whhCB : whhCF; whh8 = dir ? w8CB : w8CF; pre = preC; doCR = true;
    } else if (u < 12) {
        dir = 0; bblk = u - 8; nsteps = TT_; t0 = 0; tstep = 1;
        whh = whhTF; whh8 = w8TF; pre = preT; tlOff = 0;
    } else {
        dir = 1; bblk = u - 12; nsteps = 1; t0 = TT_-1; tstep = -1;
        whh = nullptr; pre = preT; tlOff = 256;
    }
    const int b0 = bblk * 16;

    // ---- load all recurrent weights into registers --------------------------
    i64     w8r[6][8];   // fp8 tiles, tau order {0,1,2,3,6,7}
    bf16x8v wgr[2][8];   // bf16 g tiles, tau {4,5}
    if (whh) {
        #pragma unroll
        for (int ti = 0; ti < 6; ++ti) {
            const int tau = (ti < 4) ? ti : (ti + 2);          // 0,1,2,3,6,7
            int n = (tau >> 1)*256 + w*32 + (tau & 1)*16 + (l & 15);
            #pragma unroll
            for (int kc = 0; kc < 8; ++kc)
                w8r[ti][kc] = *(const i64*)(whh8 + (size_t)n*H_ + kc*32 + (l>>4)*8);
        }
        #pragma unroll
        for (int ti = 0; ti < 2; ++ti) {
            int n = 512 + w*32 + ti*16 + (l & 15);             // tau 4,5
            #pragma unroll
            for (int kc = 0; kc < 8; ++kc)
                wgr[ti][kc] = *(const bf16x8v*)(whh + (size_t)n*H_ + kc*32 + (l>>4)*8);
        }
    }
    for (int i = tid; i < 6144; i += 512) ((uint32_t*)smem)[i] = 0;
    __syncthreads();

    float cst[2][4];
    #pragma unroll
    for (int jt = 0; jt < 2; ++jt)
        #pragma unroll
        for (int r = 0; r < 4; ++r) cst[jt][r] = 0.f;

    const uint16_t* pb = pre + (((size_t)bblk*2 + dir)*8 + w)*2048 + (size_t)l*32;

    // prefetch step 0
    uint4 pf0, pf1, pf2, pf3;
    {
        const uint16_t* pp = pb + (size_t)t0*131072;
        pf0 = *(const uint4*)(pp);
        pf1 = *(const uint4*)(pp + 8);
        pf2 = *(const uint4*)(pp + 16);
        pf3 = *(const uint4*)(pp + 24);
    }

    for (int s = 0; s < nsteps; ++s) {
        const int t = t0 + s*tstep;
        const char* hb = smem + (s & 1)*12288;        // read buffer
        char*       ho = smem + ((s & 1) ^ 1)*12288;  // write buffer

        f32x4v acc[8];
        acc[0][0]=bf2f((uint16_t)(pf0.x&0xffff)); acc[0][1]=bf2f((uint16_t)(pf0.x>>16));
        acc[0][2]=bf2f((uint16_t)(pf0.y&0xffff)); acc[0][3]=bf2f((uint16_t)(pf0.y>>16));
        acc[1][0]=bf2f((uint16_t)(pf0.z&0xffff)); acc[1][1]=bf2f((uint16_t)(pf0.z>>16));
        acc[1][2]=bf2f((uint16_t)(pf0.w&0xffff)); acc[1][3]=bf2f((uint16_t)(pf0.w>>16));
        acc[2][0]=bf2f((uint16_t)(pf1.x&0xffff)); acc[2][1]=bf2f((uint16_t)(pf1.x>>16));
        acc[2][2]=bf2f((uint16_t)(pf1.y&0xffff)); acc[2][3]=bf2f((uint16_t)(pf1.y>>16));
        acc[3][0]=bf2f((uint16_t)(pf1.z&0xffff)); acc[3][1]=bf2f((uint16_t)(pf1.z>>16));
        acc[3][2]=bf2f((uint16_t)(pf1.w&0xffff)); acc[3][3]=bf2f((uint16_t)(pf1.w>>16));
        acc[4][0]=bf2f((uint16_t)(pf2.x&0xffff)); acc[4][1]=bf2f((uint16_t)(pf2.x>>16));
        acc[4][2]=bf2f((uint16_t)(pf2.y&0xffff)); acc[4][3]=bf2f((uint16_t)(pf2.y>>16));
        acc[5][0]=bf2f((uint16_t)(pf2.z&0xffff)); acc[5][1]=bf2f((uint16_t)(pf2.z>>16));
        acc[5][2]=bf2f((uint16_t)(pf2.w&0xffff)); acc[5][3]=bf2f((uint16_t)(pf2.w>>16));
        acc[6][0]=bf2f((uint16_t)(pf3.x&0xffff)); acc[6][1]=bf2f((uint16_t)(pf3.x>>16));
        acc[6][2]=bf2f((uint16_t)(pf3.y&0xffff)); acc[6][3]=bf2f((uint16_t)(pf3.y>>16));
        acc[7][0]=bf2f((uint16_t)(pf3.z&0xffff)); acc[7][1]=bf2f((uint16_t)(pf3.z>>16));
        acc[7][2]=bf2f((uint16_t)(pf3.w&0xffff)); acc[7][3]=bf2f((uint16_t)(pf3.w>>16));

        if (whh) {
            const int row = l & 15;
            #pragma unroll
            for (int kc = 0; kc < 8; ++kc) {
                int ab8 = (row*256 + kc*32 + (l>>4)*8)  ^ ((row & 7) << 3);
                int abf = (row*512 + kc*64 + (l>>4)*16) ^ ((row & 7) << 4);
                i64     a8 = *(const i64*)(hb + 8192 + ab8);
                bf16x8v ab = *(const bf16x8v*)(hb + abf);
                acc[0] = __builtin_amdgcn_mfma_f32_16x16x32_fp8_fp8(a8, w8r[0][kc], acc[0], 0,0,0);
                acc[1] = __builtin_amdgcn_mfma_f32_16x16x32_fp8_fp8(a8, w8r[1][kc], acc[1], 0,0,0);
                acc[2] = __builtin_amdgcn_mfma_f32_16x16x32_fp8_fp8(a8, w8r[2][kc], acc[2], 0,0,0);
                acc[3] = __builtin_amdgcn_mfma_f32_16x16x32_fp8_fp8(a8, w8r[3][kc], acc[3], 0,0,0);
                acc[4] = __builtin_amdgcn_mfma_f32_16x16x32_bf16(ab, wgr[0][kc], acc[4], 0,0,0);
                acc[5] = __builtin_amdgcn_mfma_f32_16x16x32_bf16(ab, wgr[1][kc], acc[5], 0,0,0);
                acc[6] = __builtin_amdgcn_mfma_f32_16x16x32_fp8_fp8(a8, w8r[4][kc], acc[6], 0,0,0);
                acc[7] = __builtin_amdgcn_mfma_f32_16x16x32_fp8_fp8(a8, w8r[5][kc], acc[7], 0,0,0);
            }
        }

        // prefetch next step's pre (latency hides under nonlinearity+barrier)
        if (s + 1 < nsteps) {
            const uint16_t* pp = pb + (size_t)(t + tstep)*131072;
            pf0 = *(const uint4*)(pp);
            pf1 = *(const uint4*)(pp + 8);
            pf2 = *(const uint4*)(pp + 16);
            pf3 = *(const uint4*)(pp + 24);
        }

        #pragma unroll
        for (int jt = 0; jt < 2; ++jt) {
            #pragma unroll
            for (int r = 0; r < 4; ++r) {
                float iv = acc[0+jt][r], fv = acc[2+jt][r];
                float gv = acc[4+jt][r], ov = acc[6+jt][r];
                float si = sigm(iv), sf = sigm(fv), so = sigm(ov);
                float tg = tanhx(gv);
                float cv = sf*cst[jt][r] + si*tg;
                cst[jt][r] = cv;
                float hv = so * tanhx(cv);
                uint16_t hbv = f2bf(hv);
                int m = (l >> 4)*4 + r;
                int j = w*32 + jt*16 + (l & 15);
                int obf = (m*512 + j*2) ^ ((m & 7) << 4);
                *(uint16_t*)(ho + obf) = hbv;
                int of8 = (m*256 + j) ^ ((m & 7) << 3);
                int pk8 = __builtin_amdgcn_cvt_pk_fp8_f32(hv, hv, 0, false);
                *(uint8_t*)(ho + 8192 + of8) = (uint8_t)(pk8 & 0xff);
                if (doCR)
                    cr[((size_t)(b0 + m)*TC_ + t)*512 + dir*256 + j] = hbv;
                if (tlOff >= 0 && s == nsteps-1)
                    tl[(size_t)(b0 + m)*512 + tlOff + j] = hv;
            }
        }

        // one barrier per step: LDS-only drain; global loads/stores stay in flight
        __builtin_amdgcn_sched_barrier(0);
        asm volatile("s_waitcnt lgkmcnt(0)" ::: "memory");
        __builtin_amdgcn_s_barrier();
        __builtin_amdgcn_sched_barrier(0);
    }
}

// ---------------- attention + fc + log_softmax, one block per batch --------
__global__ __launch_bounds__(256) void k_attn(const uint16_t* __restrict__ cr,
        const float* __restrict__ tl, const float* __restrict__ attw,
        const float* __restrict__ fcw, const float* __restrict__ fcb,
        float* __restrict__ out)
{
    __shared__ float sT[512];
    __shared__ float sQ[512];
    __shared__ float sS[640];
    __shared__ float sR[256];
    const int b = blockIdx.x, tid = threadIdx.x;
    for (int i = tid; i < 512; i += 256) sT[i] = tl[(size_t)b*512 + i];
    __syncthreads();
    for (int n = tid; n < 512; n += 256) {
        float s = 0.f;
        for (int j = 0; j < 512; ++j) s += sT[j] * attw[(size_t)j*512 + n];
        sQ[n] = s;
    }
    __syncthreads();
    for (int t = tid; t < TC_; t += 256) {
        const uint16_t* row = cr + ((size_t)b*TC_ + t)*512;
        float s = 0.f;
        for (int c = 0; c < 64; ++c) {
            uint4 v = *(const uint4*)(row + c*8);
            uint32_t d;
            d = v.x; s += bf2f((uint16_t)(d&0xffff))*sQ[c*8+0] + bf2f((uint16_t)(d>>16))*sQ[c*8+1];
            d = v.y; s += bf2f((uint16_t)(d&0xffff))*sQ[c*8+2] + bf2f((uint16_t)(d>>16))*sQ[c*8+3];
            d = v.z; s += bf2f((uint16_t)(d&0xffff))*sQ[c*8+4] + bf2f((uint16_t)(d>>16))*sQ[c*8+5];
            d = v.w; s += bf2f((uint16_t)(d&0xffff))*sQ[c*8+6] + bf2f((uint16_t)(d>>16))*sQ[c*8+7];
        }
        sS[t] = s;
    }
    __syncthreads();
    float lm = -1e30f;
    for (int t = tid; t < TC_; t += 256) lm = fmaxf(lm, sS[t]);
    sR[tid] = lm; __syncthreads();
    for (int o = 128; o > 0; o >>= 1) { if (tid < o) sR[tid] = fmaxf(sR[tid], sR[tid+o]); __syncthreads(); }
    float M = sR[0]; __syncthreads();
    float ls = 0.f;
    for (int t = tid; t < TC_; t += 256) { float e = __expf(sS[t]-M); sS[t] = e; ls += e; }
    sR[tid] = ls; __syncthreads();
    for (int o = 128; o > 0; o >>= 1) { if (tid < o) sR[tid] += sR[tid+o]; __syncthreads(); }
    float inv = 1.f / sR[0]; __syncthreads();
    float la[5] = {0.f,0.f,0.f,0.f,0.f};
    for (int t = tid; t < TC_; t += 256) {
        float p = sS[t] * inv;
        #pragma unroll
        for (int ll = 0; ll < 5; ++ll) la[ll] += p * fcw[ll*TC_ + t];
    }
    float lg[5];
    #pragma unroll
    for (int ll = 0; ll < 5; ++ll) {
        sR[tid] = la[ll]; __syncthreads();
        for (int o = 128; o > 0; o >>= 1) { if (tid < o) sR[tid] += sR[tid+o]; __syncthreads(); }
        lg[ll] = sR[0] + fcb[ll]; __syncthreads();
    }
    if (tid == 0) {
        float m2 = lg[0];
        #pragma unroll
        for (int ll = 1; ll < 5; ++ll) m2 = fmaxf(m2, lg[ll]);
        float se = 0.f;
        #pragma unroll
        for (int ll = 0; ll < 5; ++ll) se += __expf(lg[ll] - m2);
        float lse = __logf(se) + m2;
        #pragma unroll
        for (int ll = 0; ll < 5; ++ll) out[b*5 + ll] = lg[ll] - lse;
    }
}

// ---------------------------------------------------------------------------
extern "C" void kernel_launch(void* const* d_in, const int* in_sizes, int n_in,
                              void* d_out, int out_size, void* d_ws, size_t ws_size,
                              hipStream_t stream)
{
    const int*   content = (const int*)d_in[0];
    const int*   title   = (const int*)d_in[1];
    const float* embed_w = (const float*)d_in[2];
    const float* t_wih_f = (const float*)d_in[3];
    const float* t_whh_f = (const float*)d_in[4];
    const float* t_b_f   = (const float*)d_in[5];
    const float* t_wih_b = (const float*)d_in[6];
    const float* t_b_b   = (const float*)d_in[8];
    const float* c_wih_f = (const float*)d_in[9];
    const float* c_whh_f = (const float*)d_in[10];
    const float* c_b_f   = (const float*)d_in[11];
    const float* c_wih_b = (const float*)d_in[12];
    const float* c_whh_b = (const float*)d_in[13];
    const float* c_b_b   = (const float*)d_in[14];
    const float* att_w   = (const float*)d_in[15];
    const float* fc_w    = (const float*)d_in[16];
    const float* fc_b    = (const float*)d_in[17];
    float* out = (float*)d_out;

    char* ws = (char*)d_ws;
    size_t o = 0;
    auto alloc = [&](size_t sz) { char* p = ws + o; o = (o + sz + 255) & ~(size_t)255; return p; };
    uint16_t* Ac    = (uint16_t*)alloc((size_t)40832*KP_*2);
    uint16_t* At    = (uint16_t*)alloc((size_t)1536*KP_*2);
    uint16_t* BwC   = (uint16_t*)alloc((size_t)NG_*KP_*2);
    uint16_t* BwT   = (uint16_t*)alloc((size_t)NG_*KP_*2);
    float*    biasC = (float*)   alloc((size_t)NG_*4);
    float*    biasT = (float*)   alloc((size_t)NG_*4);
    uint16_t* whhCF = (uint16_t*)alloc((size_t)1024*H_*2);
    uint16_t* whhCB = (uint16_t*)alloc((size_t)1024*H_*2);
    uint16_t* whhTF = (uint16_t*)alloc((size_t)1024*H_*2);
    uint8_t*  w8CF  = (uint8_t*) alloc((size_t)1024*H_);
    uint8_t*  w8CB  = (uint8_t*) alloc((size_t)1024*H_);
    uint8_t*  w8TF  = (uint8_t*) alloc((size_t)1024*H_);
    uint16_t* preC  = (uint16_t*)alloc((size_t)TCP_*262144);
    uint16_t* preT  = (uint16_t*)alloc((size_t)TT_*262144);
    uint16_t* crp   = (uint16_t*)alloc((size_t)B_*TC_*512*2);
    float*    tlp   = (float*)   alloc((size_t)B_*512*4);

    k_prep<<<256, 256, 0, stream>>>(t_wih_f, t_wih_b, t_whh_f, c_wih_f, c_wih_b,
                                    c_whh_f, c_whh_b, t_b_f, t_b_b, c_b_f, c_b_b,
                                    BwC, BwT, biasC, biasT, whhCF, whhCB, whhTF,
                                    (uint32_t*)w8CF, (uint32_t*)w8CB, (uint32_t*)w8TF);
    k_gather<<<2048, 256, 0, stream>>>(content, title, embed_w, Ac, At);
    k_gemm<<<dim3(16, 319), 256, 0, stream>>>(Ac, BwC, biasC, preC);
    k_gemm<<<dim3(16, 12),  256, 0, stream>>>(At, BwT, biasT, preT);
    k_rnn<<<16, 512, 0, stream>>>(preC, preT, whhCF, whhCB, whhTF,
                                  w8CF, w8CB, w8TF, crp, tlp);
    k_attn<<<64, 256, 0, stream>>>(crp, tlp, att_w, fc_w, fc_b, out);
}

// Round 3
// 2079.019 us; speedup vs baseline: 1.2472x; 1.0817x over previous
//
#include <hip/hip_runtime.h>
#include <stdint.h>

typedef __attribute__((ext_vector_type(8))) short bf16x8v;
typedef __attribute__((ext_vector_type(4))) float f32x4v;
typedef long long i64;

#define DEV static __device__ __forceinline__

#define B_   64
#define TC_  637
#define TCP_ 638
#define TT_  24
#define E_   300
#define KP_  320
#define H_   256
#define NG_  2048

DEV uint16_t f2bf(float f) {
    uint32_t u = __float_as_uint(f);
    u += 0x7fffu + ((u >> 16) & 1u);
    return (uint16_t)(u >> 16);
}
DEV float bf2f(uint16_t h) { return __uint_as_float(((uint32_t)h) << 16); }
// exp2-based: sigm = 4 VALU, tanh = 5 VALU
DEV float sigm(float x)  { return __builtin_amdgcn_rcpf(1.f + __builtin_amdgcn_exp2f(x * -1.4426950408889634f)); }
DEV float tanhx(float x) { return 1.f - 2.f*__builtin_amdgcn_rcpf(1.f + __builtin_amdgcn_exp2f(x * 2.8853900817779268f)); }

DEV void gload_lds16(const void* g, void* l) {
    __builtin_amdgcn_global_load_lds((const __attribute__((address_space(1))) uint32_t*)g,
                                     (__attribute__((address_space(3))) uint32_t*)l, 16, 0, 0);
}

// ---------------- weight prep: wih fp32->bf16 (+K-pad), whh fp32->fp8 -------
__global__ void k_prep(const float* t_wih_f, const float* t_wih_b,
                       const float* t_whh_f,
                       const float* c_wih_f, const float* c_wih_b,
                       const float* c_whh_f, const float* c_whh_b,
                       const float* t_b_f, const float* t_b_b,
                       const float* c_b_f, const float* c_b_b,
                       uint16_t* BwC, uint16_t* BwT, float* biasC, float* biasT,
                       uint32_t* w8CF, uint32_t* w8CB, uint32_t* w8TF)
{
    int tid = blockIdx.x*blockDim.x + threadIdx.x;
    int nth = gridDim.x*blockDim.x;
    for (int i = tid; i < NG_*KP_; i += nth) {
        int n = i / KP_, k = i - n*KP_;
        float vc = 0.f, vt = 0.f;
        if (k < E_) {
            vc = (n < 1024) ? c_wih_f[n*E_+k] : c_wih_b[(n-1024)*E_+k];
            vt = (n < 1024) ? t_wih_f[n*E_+k] : t_wih_b[(n-1024)*E_+k];
        }
        BwC[i] = f2bf(vc); BwT[i] = f2bf(vt);
    }
    for (int i = tid; i < 1024*H_/4; i += nth) {    // fp8 whh (all gates)
        int base = i*4;
        uint32_t a, b, c;
        a = (uint32_t)__builtin_amdgcn_cvt_pk_fp8_f32(c_whh_f[base], c_whh_f[base+1], 0, false);
        a = (uint32_t)__builtin_amdgcn_cvt_pk_fp8_f32(c_whh_f[base+2], c_whh_f[base+3], (int)a, true);
        b = (uint32_t)__builtin_amdgcn_cvt_pk_fp8_f32(c_whh_b[base], c_whh_b[base+1], 0, false);
        b = (uint32_t)__builtin_amdgcn_cvt_pk_fp8_f32(c_whh_b[base+2], c_whh_b[base+3], (int)b, true);
        c = (uint32_t)__builtin_amdgcn_cvt_pk_fp8_f32(t_whh_f[base], t_whh_f[base+1], 0, false);
        c = (uint32_t)__builtin_amdgcn_cvt_pk_fp8_f32(t_whh_f[base+2], t_whh_f[base+3], (int)c, true);
        w8CF[i] = a; w8CB[i] = b; w8TF[i] = c;
    }
    for (int i = tid; i < NG_; i += nth) {
        biasC[i] = (i < 1024) ? c_b_f[i] : c_b_b[i-1024];
        biasT[i] = (i < 1024) ? t_b_f[i] : t_b_b[i-1024];
    }
}

// ---------------- embedding gather -> bf16 A matrices (row m = t*64 + b) ----
__global__ void k_gather(const int* __restrict__ content, const int* __restrict__ title,
                         const float* __restrict__ emb,
                         uint16_t* __restrict__ Ac, uint16_t* __restrict__ At)
{
    int tid = blockIdx.x*blockDim.x + threadIdx.x;
    int nth = gridDim.x*blockDim.x;
    const int CCH = 40832*40;
    const int TCH = 1536*40;
    for (int i = tid; i < CCH + TCH; i += nth) {
        uint16_t* dst; int row, c8; int tok;
        if (i < CCH) {
            row = i / 40; c8 = i - row*40;
            int t = row >> 6, b = row & 63;
            tok = (t < TC_) ? content[b*TC_ + t] : -1;
            dst = Ac + (size_t)row*KP_ + c8*8;
        } else {
            int jx = i - CCH;
            row = jx / 40; c8 = jx - row*40;
            int t = row >> 6, b = row & 63;
            tok = title[b*TT_ + t];
            dst = At + (size_t)row*KP_ + c8*8;
        }
        uint32_t dd[4];
        #pragma unroll
        for (int p = 0; p < 4; ++p) {
            int k = c8*8 + p*2;
            float f0 = (tok >= 0 && k   < E_) ? emb[(size_t)tok*E_ + k]   : 0.f;
            float f1 = (tok >= 0 && k+1 < E_) ? emb[(size_t)tok*E_ + k+1] : 0.f;
            dd[p] = (uint32_t)f2bf(f0) | ((uint32_t)f2bf(f1) << 16);
        }
        uint4 q; q.x = dd[0]; q.y = dd[1]; q.z = dd[2]; q.w = dd[3];
        *(uint4*)dst = q;
    }
}

// ---------------- pre-GEMM: C[m][n] = sum_k A[m][k]*Bw[n][k] + bias[n] ------
// 128x128 tile, BK=32, 4 waves, double-buffered global_load_lds staging.
// Epilogue: fragment-permuted store, tau = jt*4 + type (k_rnn 16-wave layout).
__global__ __launch_bounds__(256) void k_gemm(const uint16_t* __restrict__ A,
        const uint16_t* __restrict__ Bw, const float* __restrict__ bias,
        uint16_t* __restrict__ prep)
{
    __shared__ __align__(16) uint16_t lA[2][128*32];
    __shared__ __align__(16) uint16_t lB[2][128*32];
    const int tid = threadIdx.x;
    const int l = tid & 63, wv = tid >> 6;
    const int m0 = blockIdx.y * 128, n0 = blockIdx.x * 128;

    auto stage = [&](int kc, int bi) {
        #pragma unroll
        for (int r = 0; r < 2; ++r) {
            int row = r*64 + (tid >> 2);
            int cu  = (tid & 3) * 8;
            gload_lds16(A  + (size_t)(m0 + row)*KP_ + kc*32 + cu, &lA[bi][r*2048 + wv*512]);
            gload_lds16(Bw + (size_t)(n0 + row)*KP_ + kc*32 + cu, &lB[bi][r*2048 + wv*512]);
        }
    };

    f32x4v acc[4][4];
    #pragma unroll
    for (int i = 0; i < 4; ++i)
        #pragma unroll
        for (int j = 0; j < 4; ++j)
            acc[i][j] = f32x4v{0.f,0.f,0.f,0.f};

    const int mtb = (wv >> 1) * 4, ntb = (wv & 1) * 4;

    stage(0, 0);
    __syncthreads();
    for (int kc = 0; kc < 10; ++kc) {
        if (kc < 9) stage(kc + 1, (kc + 1) & 1);
        {
            int bi = kc & 1;
            bf16x8v af[4], bfr[4];
            #pragma unroll
            for (int i = 0; i < 4; ++i) {
                af[i]  = *(const bf16x8v*)&lA[bi][((mtb+i)*16 + (l&15))*32 + (l>>4)*8];
                bfr[i] = *(const bf16x8v*)&lB[bi][((ntb+i)*16 + (l&15))*32 + (l>>4)*8];
            }
            #pragma unroll
            for (int i = 0; i < 4; ++i)
                #pragma unroll
                for (int j = 0; j < 4; ++j)
                    acc[i][j] = __builtin_amdgcn_mfma_f32_16x16x32_bf16(af[i], bfr[j], acc[i][j], 0,0,0);
        }
        __syncthreads();
    }

    #pragma unroll
    for (int j = 0; j < 4; ++j) {
        int nt = ntb + j;
        int n  = n0 + nt*16;
        int dir  = n >> 10;
        int nj   = n & 1023;
        int type = nj >> 8;
        int w    = (nj >> 5) & 7;
        int jt   = (nj >> 4) & 1;
        int tau  = jt*4 + type;
        float bv = bias[n + (l & 15)];
        #pragma unroll
        for (int i = 0; i < 4; ++i) {
            int mt   = mtb + i;
            int row0 = mt*16 + (l >> 4)*4;
            int t    = (m0 + row0) >> 6;
            int bblk = mt & 3;
            ushort4 pk;
            pk.x = f2bf(acc[i][j][0] + bv);
            pk.y = f2bf(acc[i][j][1] + bv);
            pk.z = f2bf(acc[i][j][2] + bv);
            pk.w = f2bf(acc[i][j][3] + bv);
            size_t off = ((((size_t)t*4 + bblk)*2 + dir)*8 + w)*2048 + (size_t)l*32 + tau*4;
            *(ushort4*)(prep + off) = pk;
        }
    }
}

// ---------------- recurrence: one block per (direction, 16-batch) unit ------
// 16 waves x 64 lanes. Each wave owns 64 gate-cols = 4 fp8 weight tiles
// (64 VGPRs, guaranteed register-resident at the 128-reg class).
// h: fp8-only, double-buffered 2x4KB LDS, conflict-free bit5-6 XOR swizzle.
// One lgkm-only barrier per step; pre prefetched one step ahead.
__global__ __launch_bounds__(1024, 4) void k_rnn(
    const uint16_t* __restrict__ preC, const uint16_t* __restrict__ preT,
    const uint8_t* __restrict__ w8CF, const uint8_t* __restrict__ w8CB,
    const uint8_t* __restrict__ w8TF,
    uint16_t* __restrict__ cr, float* __restrict__ tl)
{
    __shared__ __align__(16) char smem[16384];   // 2 x 8KB fp8-h buffers

    const int tid = threadIdx.x;
    const int l = tid & 63, wvv = tid >> 6;      // wvv 0..15
    const int w = wvv >> 1, jt = wvv & 1;
    const int u = blockIdx.x;

    int dir, bblk, t0, tstep, nsteps, tlOff = -1;
    bool doCR = false;
    const uint16_t* pre; const uint8_t* whh8 = nullptr;
    if (u < 8) {
        dir = u & 1; bblk = u >> 1;
        nsteps = TC_; t0 = dir ? (TC_-1) : 0; tstep = dir ? -1 : 1;
        whh8 = dir ? w8CB : w8CF; pre = preC; doCR = true;
    } else if (u < 12) {
        dir = 0; bblk = u - 8; nsteps = TT_; t0 = 0; tstep = 1;
        whh8 = w8TF; pre = preT; tlOff = 0;
    } else {
        dir = 1; bblk = u - 12; nsteps = 1; t0 = TT_-1; tstep = -1;
        whh8 = nullptr; pre = preT; tlOff = 256;
    }
    const int b0 = bblk * 16;

    // ---- weights: 4 fp8 tiles {i,f,g,o} for this wave's 16 columns ---------
    i64 w8r[4][8];
    if (whh8) {
        #pragma unroll
        for (int ty = 0; ty < 4; ++ty) {
            int n = ty*256 + w*32 + jt*16 + (l & 15);
            #pragma unroll
            for (int kc = 0; kc < 8; ++kc)
                w8r[ty][kc] = *(const i64*)(whh8 + (size_t)n*H_ + kc*32 + (l>>4)*8);
        }
    }
    for (int i = tid; i < 4096; i += 1024) ((uint32_t*)smem)[i] = 0;
    __syncthreads();

    // ---- per-lane constants -------------------------------------------------
    const int row = l & 15, hi = l >> 4;
    const int j = w*32 + jt*16 + row;                      // this lane's column
    // A-fragment read base: addr(kc) = rdb ^ (kc*32); bits5-6 swizzle by row&3
    const int rdb = row*256 + hi*8 + ((row & 3) << 5);
    int wa[4];                                             // h write addrs
    uint16_t* crp[4];
    #pragma unroll
    for (int r = 0; r < 4; ++r) {
        int m = hi*4 + r;
        wa[r] = m*256 + (j ^ ((m & 3) << 5));
        crp[r] = cr + ((size_t)(b0 + m)*TC_ + t0)*512 + dir*256 + j;
    }
    const int crAdv = tstep * 512;

    float cst[4] = {0.f, 0.f, 0.f, 0.f};

    const uint16_t* pp = pre + ((((size_t)t0*4 + bblk)*2 + dir)*8 + w)*2048
                             + (size_t)l*32 + jt*16;
    const intptr_t ppAdv = (intptr_t)tstep * 131072;

    uint4 pf0 = *(const uint4*)(pp);
    uint4 pf1 = *(const uint4*)(pp + 8);

    for (int s = 0; s < nsteps; ++s) {
        const char* hb = smem + (s & 1)*8192;
        char*       ho = smem + ((s & 1) ^ 1)*8192;

        f32x4v acc[4];
        acc[0][0]=bf2f((uint16_t)(pf0.x&0xffff)); acc[0][1]=bf2f((uint16_t)(pf0.x>>16));
        acc[0][2]=bf2f((uint16_t)(pf0.y&0xffff)); acc[0][3]=bf2f((uint16_t)(pf0.y>>16));
        acc[1][0]=bf2f((uint16_t)(pf0.z&0xffff)); acc[1][1]=bf2f((uint16_t)(pf0.z>>16));
        acc[1][2]=bf2f((uint16_t)(pf0.w&0xffff)); acc[1][3]=bf2f((uint16_t)(pf0.w>>16));
        acc[2][0]=bf2f((uint16_t)(pf1.x&0xffff)); acc[2][1]=bf2f((uint16_t)(pf1.x>>16));
        acc[2][2]=bf2f((uint16_t)(pf1.y&0xffff)); acc[2][3]=bf2f((uint16_t)(pf1.y>>16));
        acc[3][0]=bf2f((uint16_t)(pf1.z&0xffff)); acc[3][1]=bf2f((uint16_t)(pf1.z>>16));
        acc[3][2]=bf2f((uint16_t)(pf1.w&0xffff)); acc[3][3]=bf2f((uint16_t)(pf1.w>>16));

        if (whh8) {
            #pragma unroll
            for (int kc = 0; kc < 8; ++kc) {
                i64 a8 = *(const i64*)(hb + (rdb ^ (kc*32)));
                acc[0] = __builtin_amdgcn_mfma_f32_16x16x32_fp8_fp8(a8, w8r[0][kc], acc[0], 0,0,0);
                acc[1] = __builtin_amdgcn_mfma_f32_16x16x32_fp8_fp8(a8, w8r[1][kc], acc[1], 0,0,0);
                acc[2] = __builtin_amdgcn_mfma_f32_16x16x32_fp8_fp8(a8, w8r[2][kc], acc[2], 0,0,0);
                acc[3] = __builtin_amdgcn_mfma_f32_16x16x32_fp8_fp8(a8, w8r[3][kc], acc[3], 0,0,0);
            }
        }

        if (s + 1 < nsteps) {
            pp += ppAdv;
            pf0 = *(const uint4*)(pp);
            pf1 = *(const uint4*)(pp + 8);
        }

        const bool lastT = (tlOff >= 0) && (s == nsteps - 1);
        #pragma unroll
        for (int r = 0; r < 4; ++r) {
            float iv = acc[0][r], fv = acc[1][r];
            float gv = acc[2][r], ov = acc[3][r];
            float si = sigm(iv), sf = sigm(fv), so = sigm(ov);
            float tg = tanhx(gv);
            float cv = sf*cst[r] + si*tg;
            cst[r] = cv;
            float hv = so * tanhx(cv);
            int pk8 = __builtin_amdgcn_cvt_pk_fp8_f32(hv, hv, 0, false);
            *(uint8_t*)(ho + wa[r]) = (uint8_t)pk8;
            if (doCR) { *crp[r] = f2bf(hv); crp[r] += crAdv; }
            if (lastT) tl[(size_t)(b0 + hi*4 + r)*512 + tlOff + j] = hv;
        }

        __builtin_amdgcn_sched_barrier(0);
        asm volatile("s_waitcnt lgkmcnt(0)" ::: "memory");
        __builtin_amdgcn_s_barrier();
        __builtin_amdgcn_sched_barrier(0);
    }
}

// ---------------- attention + fc + log_softmax, one block per batch --------
__global__ __launch_bounds__(256) void k_attn(const uint16_t* __restrict__ cr,
        const float* __restrict__ tl, const float* __restrict__ attw,
        const float* __restrict__ fcw, const float* __restrict__ fcb,
        float* __restrict__ out)
{
    __shared__ float sT[512];
    __shared__ float sQ[512];
    __shared__ float sS[640];
    __shared__ float sR[256];
    const int b = blockIdx.x, tid = threadIdx.x;
    for (int i = tid; i < 512; i += 256) sT[i] = tl[(size_t)b*512 + i];
    __syncthreads();
    for (int n = tid; n < 512; n += 256) {
        float s = 0.f;
        for (int j = 0; j < 512; ++j) s += sT[j] * attw[(size_t)j*512 + n];
        sQ[n] = s;
    }
    __syncthreads();
    for (int t = tid; t < TC_; t += 256) {
        const uint16_t* row = cr + ((size_t)b*TC_ + t)*512;
        float s = 0.f;
        for (int c = 0; c < 64; ++c) {
            uint4 v = *(const uint4*)(row + c*8);
            uint32_t d;
            d = v.x; s += bf2f((uint16_t)(d&0xffff))*sQ[c*8+0] + bf2f((uint16_t)(d>>16))*sQ[c*8+1];
            d = v.y; s += bf2f((uint16_t)(d&0xffff))*sQ[c*8+2] + bf2f((uint16_t)(d>>16))*sQ[c*8+3];
            d = v.z; s += bf2f((uint16_t)(d&0xffff))*sQ[c*8+4] + bf2f((uint16_t)(d>>16))*sQ[c*8+5];
            d = v.w; s += bf2f((uint16_t)(d&0xffff))*sQ[c*8+6] + bf2f((uint16_t)(d>>16))*sQ[c*8+7];
        }
        sS[t] = s;
    }
    __syncthreads();
    float lm = -1e30f;
    for (int t = tid; t < TC_; t += 256) lm = fmaxf(lm, sS[t]);
    sR[tid] = lm; __syncthreads();
    for (int o = 128; o > 0; o >>= 1) { if (tid < o) sR[tid] = fmaxf(sR[tid], sR[tid+o]); __syncthreads(); }
    float M = sR[0]; __syncthreads();
    float ls = 0.f;
    for (int t = tid; t < TC_; t += 256) { float e = __expf(sS[t]-M); sS[t] = e; ls += e; }
    sR[tid] = ls; __syncthreads();
    for (int o = 128; o > 0; o >>= 1) { if (tid < o) sR[tid] += sR[tid+o]; __syncthreads(); }
    float inv = 1.f / sR[0]; __syncthreads();
    float la[5] = {0.f,0.f,0.f,0.f,0.f};
    for (int t = tid; t < TC_; t += 256) {
        float p = sS[t] * inv;
        #pragma unroll
        for (int ll = 0; ll < 5; ++ll) la[ll] += p * fcw[ll*TC_ + t];
    }
    float lg[5];
    #pragma unroll
    for (int ll = 0; ll < 5; ++ll) {
        sR[tid] = la[ll]; __syncthreads();
        for (int o = 128; o > 0; o >>= 1) { if (tid < o) sR[tid] += sR[tid+o]; __syncthreads(); }
        lg[ll] = sR[0] + fcb[ll]; __syncthreads();
    }
    if (tid == 0) {
        float m2 = lg[0];
        #pragma unroll
        for (int ll = 1; ll < 5; ++ll) m2 = fmaxf(m2, lg[ll]);
        float se = 0.f;
        #pragma unroll
        for (int ll = 0; ll < 5; ++ll) se += __expf(lg[ll] - m2);
        float lse = __logf(se) + m2;
        #pragma unroll
        for (int ll = 0; ll < 5; ++ll) out[b*5 + ll] = lg[ll] - lse;
    }
}

// ---------------------------------------------------------------------------
extern "C" void kernel_launch(void* const* d_in, const int* in_sizes, int n_in,
                              void* d_out, int out_size, void* d_ws, size_t ws_size,
                              hipStream_t stream)
{
    const int*   content = (const int*)d_in[0];
    const int*   title   = (const int*)d_in[1];
    const float* embed_w = (const float*)d_in[2];
    const float* t_wih_f = (const float*)d_in[3];
    const float* t_whh_f = (const float*)d_in[4];
    const float* t_b_f   = (const float*)d_in[5];
    const float* t_wih_b = (const float*)d_in[6];
    const float* t_b_b   = (const float*)d_in[8];
    const float* c_wih_f = (const float*)d_in[9];
    const float* c_whh_f = (const float*)d_in[10];
    const float* c_b_f   = (const float*)d_in[11];
    const float* c_wih_b = (const float*)d_in[12];
    const float* c_whh_b = (const float*)d_in[13];
    const float* c_b_b   = (const float*)d_in[14];
    const float* att_w   = (const float*)d_in[15];
    const float* fc_w    = (const float*)d_in[16];
    const float* fc_b    = (const float*)d_in[17];
    float* out = (float*)d_out;

    char* ws = (char*)d_ws;
    size_t o = 0;
    auto alloc = [&](size_t sz) { char* p = ws + o; o = (o + sz + 255) & ~(size_t)255; return p; };
    uint16_t* Ac    = (uint16_t*)alloc((size_t)40832*KP_*2);
    uint16_t* At    = (uint16_t*)alloc((size_t)1536*KP_*2);
    uint16_t* BwC   = (uint16_t*)alloc((size_t)NG_*KP_*2);
    uint16_t* BwT   = (uint16_t*)alloc((size_t)NG_*KP_*2);
    float*    biasC = (float*)   alloc((size_t)NG_*4);
    float*    biasT = (float*)   alloc((size_t)NG_*4);
    uint8_t*  w8CF  = (uint8_t*) alloc((size_t)1024*H_);
    uint8_t*  w8CB  = (uint8_t*) alloc((size_t)1024*H_);
    uint8_t*  w8TF  = (uint8_t*) alloc((size_t)1024*H_);
    uint16_t* preC  = (uint16_t*)alloc((size_t)TCP_*262144);
    uint16_t* preT  = (uint16_t*)alloc((size_t)TT_*262144);
    uint16_t* crp   = (uint16_t*)alloc((size_t)B_*TC_*512*2);
    float*    tlp   = (float*)   alloc((size_t)B_*512*4);

    k_prep<<<256, 256, 0, stream>>>(t_wih_f, t_wih_b, t_whh_f, c_wih_f, c_wih_b,
                                    c_whh_f, c_whh_b, t_b_f, t_b_b, c_b_f, c_b_b,
                                    BwC, BwT, biasC, biasT,
                                    (uint32_t*)w8CF, (uint32_t*)w8CB, (uint32_t*)w8TF);
    k_gather<<<2048, 256, 0, stream>>>(content, title, embed_w, Ac, At);
    k_gemm<<<dim3(16, 319), 256, 0, stream>>>(Ac, BwC, biasC, preC);
    k_gemm<<<dim3(16, 12),  256, 0, stream>>>(At, BwT, biasT, preT);
    k_rnn<<<16, 1024, 0, stream>>>(preC, preT, w8CF, w8CB, w8TF, crp, tlp);
    k_attn<<<64, 256, 0, stream>>>(crp, tlp, att_w, fc_w, fc_b, out);
}

// Round 4
// 1695.603 us; speedup vs baseline: 1.5292x; 1.2261x over previous
//
#include <hip/hip_runtime.h>
#include <stdint.h>

typedef __attribute__((ext_vector_type(8))) short bf16x8v;
typedef __attribute__((ext_vector_type(4))) float f32x4v;
typedef long long i64;

#define DEV static __device__ __forceinline__

#define B_   64
#define TC_  637
#define TCP_ 638
#define TT_  24
#define E_   300
#define KP_  320
#define H_   256
#define NG_  2048

DEV uint16_t f2bf(float f) {
    uint32_t u = __float_as_uint(f);
    u += 0x7fffu + ((u >> 16) & 1u);
    return (uint16_t)(u >> 16);
}
DEV float bf2f(uint16_t h) { return __uint_as_float(((uint32_t)h) << 16); }
// exp2-based: sigm = 4 VALU, tanh = 5 VALU
DEV float sigm(float x)  { return __builtin_amdgcn_rcpf(1.f + __builtin_amdgcn_exp2f(x * -1.4426950408889634f)); }
DEV float tanhx(float x) { return 1.f - 2.f*__builtin_amdgcn_rcpf(1.f + __builtin_amdgcn_exp2f(x * 2.8853900817779268f)); }

DEV void gload_lds16(const void* g, void* l) {
    __builtin_amdgcn_global_load_lds((const __attribute__((address_space(1))) uint32_t*)g,
                                     (__attribute__((address_space(3))) uint32_t*)l, 16, 0, 0);
}

// ---------------- weight prep: wih fp32->bf16 (+K-pad), whh fp32->fp8 -------
__global__ void k_prep(const float* t_wih_f, const float* t_wih_b,
                       const float* t_whh_f,
                       const float* c_wih_f, const float* c_wih_b,
                       const float* c_whh_f, const float* c_whh_b,
                       const float* t_b_f, const float* t_b_b,
                       const float* c_b_f, const float* c_b_b,
                       uint16_t* BwC, uint16_t* BwT, float* biasC, float* biasT,
                       uint32_t* w8CF, uint32_t* w8CB, uint32_t* w8TF)
{
    int tid = blockIdx.x*blockDim.x + threadIdx.x;
    int nth = gridDim.x*blockDim.x;
    for (int i = tid; i < NG_*KP_; i += nth) {
        int n = i / KP_, k = i - n*KP_;
        float vc = 0.f, vt = 0.f;
        if (k < E_) {
            vc = (n < 1024) ? c_wih_f[n*E_+k] : c_wih_b[(n-1024)*E_+k];
            vt = (n < 1024) ? t_wih_f[n*E_+k] : t_wih_b[(n-1024)*E_+k];
        }
        BwC[i] = f2bf(vc); BwT[i] = f2bf(vt);
    }
    for (int i = tid; i < 1024*H_/4; i += nth) {    // fp8 whh (all gates)
        int base = i*4;
        uint32_t a, b, c;
        a = (uint32_t)__builtin_amdgcn_cvt_pk_fp8_f32(c_whh_f[base], c_whh_f[base+1], 0, false);
        a = (uint32_t)__builtin_amdgcn_cvt_pk_fp8_f32(c_whh_f[base+2], c_whh_f[base+3], (int)a, true);
        b = (uint32_t)__builtin_amdgcn_cvt_pk_fp8_f32(c_whh_b[base], c_whh_b[base+1], 0, false);
        b = (uint32_t)__builtin_amdgcn_cvt_pk_fp8_f32(c_whh_b[base+2], c_whh_b[base+3], (int)b, true);
        c = (uint32_t)__builtin_amdgcn_cvt_pk_fp8_f32(t_whh_f[base], t_whh_f[base+1], 0, false);
        c = (uint32_t)__builtin_amdgcn_cvt_pk_fp8_f32(t_whh_f[base+2], t_whh_f[base+3], (int)c, true);
        w8CF[i] = a; w8CB[i] = b; w8TF[i] = c;
    }
    for (int i = tid; i < NG_; i += nth) {
        biasC[i] = (i < 1024) ? c_b_f[i] : c_b_b[i-1024];
        biasT[i] = (i < 1024) ? t_b_f[i] : t_b_b[i-1024];
    }
}

// ---------------- embedding gather -> bf16 A matrices (row m = t*64 + b) ----
__global__ void k_gather(const int* __restrict__ content, const int* __restrict__ title,
                         const float* __restrict__ emb,
                         uint16_t* __restrict__ Ac, uint16_t* __restrict__ At)
{
    int tid = blockIdx.x*blockDim.x + threadIdx.x;
    int nth = gridDim.x*blockDim.x;
    const int CCH = 40832*40;
    const int TCH = 1536*40;
    for (int i = tid; i < CCH + TCH; i += nth) {
        uint16_t* dst; int row, c8; int tok;
        if (i < CCH) {
            row = i / 40; c8 = i - row*40;
            int t = row >> 6, b = row & 63;
            tok = (t < TC_) ? content[b*TC_ + t] : -1;
            dst = Ac + (size_t)row*KP_ + c8*8;
        } else {
            int jx = i - CCH;
            row = jx / 40; c8 = jx - row*40;
            int t = row >> 6, b = row & 63;
            tok = title[b*TT_ + t];
            dst = At + (size_t)row*KP_ + c8*8;
        }
        uint32_t dd[4];
        #pragma unroll
        for (int p = 0; p < 4; ++p) {
            int k = c8*8 + p*2;
            float f0 = (tok >= 0 && k   < E_) ? emb[(size_t)tok*E_ + k]   : 0.f;
            float f1 = (tok >= 0 && k+1 < E_) ? emb[(size_t)tok*E_ + k+1] : 0.f;
            dd[p] = (uint32_t)f2bf(f0) | ((uint32_t)f2bf(f1) << 16);
        }
        uint4 q; q.x = dd[0]; q.y = dd[1]; q.z = dd[2]; q.w = dd[3];
        *(uint4*)dst = q;
    }
}

// ---------------- pre-GEMM: swapped operands: D = W-tile x act^T ------------
// 128x128 tile, BK=32, 4 waves, double-buffered global_load_lds staging.
// D[n_local][m]: lane = batch col, regs = 4 consecutive gate cols.
// Epilogue: fragment-permuted store [unit][w'][lane][ty][r] (k_rnn layout).
__global__ __launch_bounds__(256) void k_gemm(const uint16_t* __restrict__ A,
        const uint16_t* __restrict__ Bw, const float* __restrict__ bias,
        uint16_t* __restrict__ prep)
{
    __shared__ __align__(16) uint16_t lA[2][128*32];
    __shared__ __align__(16) uint16_t lB[2][128*32];
    const int tid = threadIdx.x;
    const int l = tid & 63, wv = tid >> 6;
    const int m0 = blockIdx.y * 128, n0 = blockIdx.x * 128;

    auto stage = [&](int kc, int bi) {
        #pragma unroll
        for (int r = 0; r < 2; ++r) {
            int row = r*64 + (tid >> 2);
            int cu  = (tid & 3) * 8;
            gload_lds16(A  + (size_t)(m0 + row)*KP_ + kc*32 + cu, &lA[bi][r*2048 + wv*512]);
            gload_lds16(Bw + (size_t)(n0 + row)*KP_ + kc*32 + cu, &lB[bi][r*2048 + wv*512]);
        }
    };

    f32x4v acc[4][4];
    #pragma unroll
    for (int i = 0; i < 4; ++i)
        #pragma unroll
        for (int j = 0; j < 4; ++j)
            acc[i][j] = f32x4v{0.f,0.f,0.f,0.f};

    const int mtb = (wv >> 1) * 4, ntb = (wv & 1) * 4;

    stage(0, 0);
    __syncthreads();
    for (int kc = 0; kc < 10; ++kc) {
        if (kc < 9) stage(kc + 1, (kc + 1) & 1);
        {
            int bi = kc & 1;
            bf16x8v af[4], bfr[4];
            #pragma unroll
            for (int i = 0; i < 4; ++i) {
                af[i]  = *(const bf16x8v*)&lA[bi][((mtb+i)*16 + (l&15))*32 + (l>>4)*8];
                bfr[i] = *(const bf16x8v*)&lB[bi][((ntb+i)*16 + (l&15))*32 + (l>>4)*8];
            }
            // swapped: A-operand = weight fragment, B-operand = activation
            #pragma unroll
            for (int i = 0; i < 4; ++i)
                #pragma unroll
                for (int j = 0; j < 4; ++j)
                    acc[i][j] = __builtin_amdgcn_mfma_f32_16x16x32_bf16(bfr[j], af[i], acc[i][j], 0,0,0);
        }
        __syncthreads();
    }

    // epilogue: D[n_local = hi*4+r][m = l&15]; store ushort4 per (i,j)
    const int hi = l >> 4;
    #pragma unroll
    for (int j = 0; j < 4; ++j) {
        int n16 = (n0 >> 4) + ntb + j;      // col-tile index 0..127
        int dir = n16 >> 6;
        int q   = n16 & 63;
        int ty  = q >> 4;
        int wp  = q & 15;
        float4 bv = *(const float4*)(bias + n16*16 + hi*4);
        #pragma unroll
        for (int i = 0; i < 4; ++i) {
            int rowblk = (m0 >> 4) + mtb + i;   // 16-row block index
            int t    = rowblk >> 2;
            int bblk = rowblk & 3;
            int unit = t*8 + bblk*2 + dir;
            ushort4 pk;
            pk.x = f2bf(acc[i][j][0] + bv.x);
            pk.y = f2bf(acc[i][j][1] + bv.y);
            pk.z = f2bf(acc[i][j][2] + bv.z);
            pk.w = f2bf(acc[i][j][3] + bv.w);
            size_t off = (size_t)unit*16384 + (size_t)wp*1024 + (size_t)l*16 + ty*4;
            *(ushort4*)(prep + off) = pk;
        }
    }
}

// ---------------- recurrence: one block per (direction, 16-batch) unit ------
// 16 waves x 64 lanes. Wave wp owns h-cols [wp*16, wp*16+16) for all 4 gate
// types = 4 fp8 tiles = 64 AGPRs (pinned via inline-asm "a" constraints --
// the compiler cannot demote AGPRs to reloads). h: fp8, 2x4KB LDS dbuf,
// (m&3)<<5 XOR swizzle. D = W x h^T: lane = batch m (l&15), regs = 4
// consecutive h-cols -> packed u32 LDS write, 8B cr store, float4 tl store.
__global__ __launch_bounds__(1024, 4) void k_rnn(
    const uint16_t* __restrict__ preC, const uint16_t* __restrict__ preT,
    const uint8_t* __restrict__ w8CF, const uint8_t* __restrict__ w8CB,
    const uint8_t* __restrict__ w8TF,
    uint16_t* __restrict__ cr, float* __restrict__ tl)
{
    __shared__ __align__(16) char smem[8192];   // 2 x 4KB fp8-h buffers

    const int tid = threadIdx.x;
    const int l = tid & 63, wp = tid >> 6;      // wp 0..15
    const int m = l & 15, hi = l >> 4;
    const int u = blockIdx.x;

    int dir, bblk, t0, tstep, nsteps, tlOff = -1;
    bool doCR = false;
    const uint16_t* pre; const uint8_t* whh8 = nullptr;
    if (u < 8) {
        dir = u & 1; bblk = u >> 1;
        nsteps = TC_; t0 = dir ? (TC_-1) : 0; tstep = dir ? -1 : 1;
        whh8 = dir ? w8CB : w8CF; pre = preC; doCR = true;
    } else if (u < 12) {
        dir = 0; bblk = u - 8; nsteps = TT_; t0 = 0; tstep = 1;
        whh8 = w8TF; pre = preT; tlOff = 0;
    } else {
        dir = 1; bblk = u - 12; nsteps = 1; t0 = TT_-1; tstep = -1;
        whh8 = nullptr; pre = preT; tlOff = 256;
    }
    const int b0 = bblk * 16;

    // ---- weights: 4 fp8 tiles {i,f,g,o} for this wave's 16 h-cols ----------
    // A-fragment: row = gate col (l&15 within tile), k = kc*32 + hi*8
    i64 w8r[4][8];
    if (whh8) {
        #pragma unroll
        for (int ty = 0; ty < 4; ++ty) {
            int n = ty*256 + wp*16 + m;
            #pragma unroll
            for (int kc = 0; kc < 8; ++kc)
                w8r[ty][kc] = *(const i64*)(whh8 + (size_t)n*H_ + kc*32 + hi*8);
        }
        // pin into AGPRs (one-time v_accvgpr_write; compiler cannot remat)
        #pragma unroll
        for (int ty = 0; ty < 4; ++ty)
            #pragma unroll
            for (int kc = 0; kc < 8; ++kc)
                asm volatile("" : "+a"(w8r[ty][kc]));
    }
    for (int i = tid; i < 2048; i += 1024) ((uint32_t*)smem)[i] = 0;
    __syncthreads();

    // ---- per-lane constants ------------------------------------------------
    const int sw = (m & 3) << 5;
    const int rdBase = m*256 + hi*8;                         // + ((kc*32)^sw)
    const int wa = m*256 + (((wp << 4) + hi*4) ^ sw);        // u32 h write
    uint16_t* crp = cr + ((size_t)(b0 + m)*TC_ + t0)*512 + dir*256 + (wp << 4) + hi*4;
    const intptr_t crAdv = (intptr_t)tstep * 512;

    float cst[4] = {0.f, 0.f, 0.f, 0.f};

    const uint16_t* pp = pre + (size_t)(t0*8 + bblk*2 + dir)*16384
                             + (size_t)(wp << 10) + (size_t)l*16;
    const intptr_t ppAdv = (intptr_t)tstep * 131072;

    uint4 pf0 = *(const uint4*)(pp);
    uint4 pf1 = *(const uint4*)(pp + 8);

    for (int s = 0; s < nsteps; ++s) {
        const char* hb = (const char*)smem + (s & 1)*4096;
        char*       ho = smem + ((s & 1) ^ 1)*4096;

        // decode pre -> acc  (acc[ty][r]; bf16 hi-half trick: 1 instr/value)
        f32x4v acc[4];
        acc[0][0]=__uint_as_float(pf0.x<<16); acc[0][1]=__uint_as_float(pf0.x&0xffff0000u);
        acc[0][2]=__uint_as_float(pf0.y<<16); acc[0][3]=__uint_as_float(pf0.y&0xffff0000u);
        acc[1][0]=__uint_as_float(pf0.z<<16); acc[1][1]=__uint_as_float(pf0.z&0xffff0000u);
        acc[1][2]=__uint_as_float(pf0.w<<16); acc[1][3]=__uint_as_float(pf0.w&0xffff0000u);
        acc[2][0]=__uint_as_float(pf1.x<<16); acc[2][1]=__uint_as_float(pf1.x&0xffff0000u);
        acc[2][2]=__uint_as_float(pf1.y<<16); acc[2][3]=__uint_as_float(pf1.y&0xffff0000u);
        acc[3][0]=__uint_as_float(pf1.z<<16); acc[3][1]=__uint_as_float(pf1.z&0xffff0000u);
        acc[3][2]=__uint_as_float(pf1.w<<16); acc[3][3]=__uint_as_float(pf1.w&0xffff0000u);

        // prefetch next step (hides under MFMA + nonlin)
        if (s + 1 < nsteps) {
            pp += ppAdv;
            pf0 = *(const uint4*)(pp);
            pf1 = *(const uint4*)(pp + 8);
        }

        if (whh8) {
            #pragma unroll
            for (int kc = 0; kc < 8; ++kc) {
                i64 a8 = *(const i64*)(hb + rdBase + ((kc << 5) ^ sw));
                asm("v_mfma_f32_16x16x32_fp8_fp8 %0, %1, %2, %0"
                    : "+v"(acc[0]) : "a"(w8r[0][kc]), "v"(a8));
                asm("v_mfma_f32_16x16x32_fp8_fp8 %0, %1, %2, %0"
                    : "+v"(acc[1]) : "a"(w8r[1][kc]), "v"(a8));
                asm("v_mfma_f32_16x16x32_fp8_fp8 %0, %1, %2, %0"
                    : "+v"(acc[2]) : "a"(w8r[2][kc]), "v"(a8));
                asm("v_mfma_f32_16x16x32_fp8_fp8 %0, %1, %2, %0"
                    : "+v"(acc[3]) : "a"(w8r[3][kc]), "v"(a8));
            }
        }

        float hv0, hv1, hv2, hv3;
        {
            float si, sf, tg, so, cv;
            si = sigm(acc[0][0]); sf = sigm(acc[1][0]); tg = tanhx(acc[2][0]); so = sigm(acc[3][0]);
            cv = sf*cst[0] + si*tg; cst[0] = cv; hv0 = so*tanhx(cv);
            si = sigm(acc[0][1]); sf = sigm(acc[1][1]); tg = tanhx(acc[2][1]); so = sigm(acc[3][1]);
            cv = sf*cst[1] + si*tg; cst[1] = cv; hv1 = so*tanhx(cv);
            si = sigm(acc[0][2]); sf = sigm(acc[1][2]); tg = tanhx(acc[2][2]); so = sigm(acc[3][2]);
            cv = sf*cst[2] + si*tg; cst[2] = cv; hv2 = so*tanhx(cv);
            si = sigm(acc[0][3]); sf = sigm(acc[1][3]); tg = tanhx(acc[2][3]); so = sigm(acc[3][3]);
            cv = sf*cst[3] + si*tg; cst[3] = cv; hv3 = so*tanhx(cv);
        }
        uint32_t p8 = (uint32_t)__builtin_amdgcn_cvt_pk_fp8_f32(hv0, hv1, 0, false);
        p8 = (uint32_t)__builtin_amdgcn_cvt_pk_fp8_f32(hv2, hv3, (int)p8, true);
        *(uint32_t*)(ho + wa) = p8;

        if (doCR) {
            uint32_t b01, b23;
            asm("v_cvt_pk_bf16_f32 %0, %1, %2" : "=v"(b01) : "v"(hv0), "v"(hv1));
            asm("v_cvt_pk_bf16_f32 %0, %1, %2" : "=v"(b23) : "v"(hv2), "v"(hv3));
            uint2 st; st.x = b01; st.y = b23;
            *(uint2*)crp = st;
            crp += crAdv;
        }
        if (tlOff >= 0 && s == nsteps - 1) {
            float4 fv; fv.x = hv0; fv.y = hv1; fv.z = hv2; fv.w = hv3;
            *(float4*)(tl + (size_t)(b0 + m)*512 + tlOff + (wp << 4) + hi*4) = fv;
        }

        // one barrier per step: LDS-only drain; global ops stay in flight
        __builtin_amdgcn_sched_barrier(0);
        asm volatile("s_waitcnt lgkmcnt(0)" ::: "memory");
        __builtin_amdgcn_s_barrier();
        __builtin_amdgcn_sched_barrier(0);
    }
}

// ---------------- attention + fc + log_softmax, one block per batch --------
__global__ __launch_bounds__(256) void k_attn(const uint16_t* __restrict__ cr,
        const float* __restrict__ tl, const float* __restrict__ attw,
        const float* __restrict__ fcw, const float* __restrict__ fcb,
        float* __restrict__ out)
{
    __shared__ float sT[512];
    __shared__ float sQ[512];
    __shared__ float sS[640];
    __shared__ float sR[256];
    const int b = blockIdx.x, tid = threadIdx.x;
    for (int i = tid; i < 512; i += 256) sT[i] = tl[(size_t)b*512 + i];
    __syncthreads();
    for (int n = tid; n < 512; n += 256) {
        float s = 0.f;
        for (int j = 0; j < 512; ++j) s += sT[j] * attw[(size_t)j*512 + n];
        sQ[n] = s;
    }
    __syncthreads();
    for (int t = tid; t < TC_; t += 256) {
        const uint16_t* row = cr + ((size_t)b*TC_ + t)*512;
        float s = 0.f;
        for (int c = 0; c < 64; ++c) {
            uint4 v = *(const uint4*)(row + c*8);
            uint32_t d;
            d = v.x; s += bf2f((uint16_t)(d&0xffff))*sQ[c*8+0] + bf2f((uint16_t)(d>>16))*sQ[c*8+1];
            d = v.y; s += bf2f((uint16_t)(d&0xffff))*sQ[c*8+2] + bf2f((uint16_t)(d>>16))*sQ[c*8+3];
            d = v.z; s += bf2f((uint16_t)(d&0xffff))*sQ[c*8+4] + bf2f((uint16_t)(d>>16))*sQ[c*8+5];
            d = v.w; s += bf2f((uint16_t)(d&0xffff))*sQ[c*8+6] + bf2f((uint16_t)(d>>16))*sQ[c*8+7];
        }
        sS[t] = s;
    }
    __syncthreads();
    float lm = -1e30f;
    for (int t = tid; t < TC_; t += 256) lm = fmaxf(lm, sS[t]);
    sR[tid] = lm; __syncthreads();
    for (int o = 128; o > 0; o >>= 1) { if (tid < o) sR[tid] = fmaxf(sR[tid], sR[tid+o]); __syncthreads(); }
    float M = sR[0]; __syncthreads();
    float ls = 0.f;
    for (int t = tid; t < TC_; t += 256) { float e = __expf(sS[t]-M); sS[t] = e; ls += e; }
    sR[tid] = ls; __syncthreads();
    for (int o = 128; o > 0; o >>= 1) { if (tid < o) sR[tid] += sR[tid+o]; __syncthreads(); }
    float inv = 1.f / sR[0]; __syncthreads();
    float la[5] = {0.f,0.f,0.f,0.f,0.f};
    for (int t = tid; t < TC_; t += 256) {
        float p = sS[t] * inv;
        #pragma unroll
        for (int ll = 0; ll < 5; ++ll) la[ll] += p * fcw[ll*TC_ + t];
    }
    float lg[5];
    #pragma unroll
    for (int ll = 0; ll < 5; ++ll) {
        sR[tid] = la[ll]; __syncthreads();
        for (int o = 128; o > 0; o >>= 1) { if (tid < o) sR[tid] += sR[tid+o]; __syncthreads(); }
        lg[ll] = sR[0] + fcb[ll]; __syncthreads();
    }
    if (tid == 0) {
        float m2 = lg[0];
        #pragma unroll
        for (int ll = 1; ll < 5; ++ll) m2 = fmaxf(m2, lg[ll]);
        float se = 0.f;
        #pragma unroll
        for (int ll = 0; ll < 5; ++ll) se += __expf(lg[ll] - m2);
        float lse = __logf(se) + m2;
        #pragma unroll
        for (int ll = 0; ll < 5; ++ll) out[b*5 + ll] = lg[ll] - lse;
    }
}

// ---------------------------------------------------------------------------
extern "C" void kernel_launch(void* const* d_in, const int* in_sizes, int n_in,
                              void* d_out, int out_size, void* d_ws, size_t ws_size,
                              hipStream_t stream)
{
    const int*   content = (const int*)d_in[0];
    const int*   title   = (const int*)d_in[1];
    const float* embed_w = (const float*)d_in[2];
    const float* t_wih_f = (const float*)d_in[3];
    const float* t_whh_f = (const float*)d_in[4];
    const float* t_b_f   = (const float*)d_in[5];
    const float* t_wih_b = (const float*)d_in[6];
    const float* t_b_b   = (const float*)d_in[8];
    const float* c_wih_f = (const float*)d_in[9];
    const float* c_whh_f = (const float*)d_in[10];
    const float* c_b_f   = (const float*)d_in[11];
    const float* c_wih_b = (const float*)d_in[12];
    const float* c_whh_b = (const float*)d_in[13];
    const float* c_b_b   = (const float*)d_in[14];
    const float* att_w   = (const float*)d_in[15];
    const float* fc_w    = (const float*)d_in[16];
    const float* fc_b    = (const float*)d_in[17];
    float* out = (float*)d_out;

    char* ws = (char*)d_ws;
    size_t o = 0;
    auto alloc = [&](size_t sz) { char* p = ws + o; o = (o + sz + 255) & ~(size_t)255; return p; };
    uint16_t* Ac    = (uint16_t*)alloc((size_t)40832*KP_*2);
    uint16_t* At    = (uint16_t*)alloc((size_t)1536*KP_*2);
    uint16_t* BwC   = (uint16_t*)alloc((size_t)NG_*KP_*2);
    uint16_t* BwT   = (uint16_t*)alloc((size_t)NG_*KP_*2);
    float*    biasC = (float*)   alloc((size_t)NG_*4);
    float*    biasT = (float*)   alloc((size_t)NG_*4);
    uint8_t*  w8CF  = (uint8_t*) alloc((size_t)1024*H_);
    uint8_t*  w8CB  = (uint8_t*) alloc((size_t)1024*H_);
    uint8_t*  w8TF  = (uint8_t*) alloc((size_t)1024*H_);
    uint16_t* preC  = (uint16_t*)alloc((size_t)TCP_*262144);
    uint16_t* preT  = (uint16_t*)alloc((size_t)TT_*262144);
    uint16_t* crp   = (uint16_t*)alloc((size_t)B_*TC_*512*2);
    float*    tlp   = (float*)   alloc((size_t)B_*512*4);

    k_prep<<<256, 256, 0, stream>>>(t_wih_f, t_wih_b, t_whh_f, c_wih_f, c_wih_b,
                                    c_whh_f, c_whh_b, t_b_f, t_b_b, c_b_f, c_b_b,
                                    BwC, BwT, biasC, biasT,
                                    (uint32_t*)w8CF, (uint32_t*)w8CB, (uint32_t*)w8TF);
    k_gather<<<2048, 256, 0, stream>>>(content, title, embed_w, Ac, At);
    k_gemm<<<dim3(16, 319), 256, 0, stream>>>(Ac, BwC, biasC, preC);
    k_gemm<<<dim3(16, 12),  256, 0, stream>>>(At, BwT, biasT, preT);
    k_rnn<<<16, 1024, 0, stream>>>(preC, preT, w8CF, w8CB, w8TF, crp, tlp);
    k_attn<<<64, 256, 0, stream>>>(crp, tlp, att_w, fc_w, fc_b, out);
}

// Round 5
// 1463.132 us; speedup vs baseline: 1.7722x; 1.1589x over previous
//
#include <hip/hip_runtime.h>
#include <stdint.h>

typedef __attribute__((ext_vector_type(8))) short bf16x8v;
typedef __attribute__((ext_vector_type(4))) float f32x4v;
typedef long long i64;
typedef __attribute__((ext_vector_type(2))) long long i64x2;

#define DEV static __device__ __forceinline__

#define B_   64
#define TC_  637
#define TCP_ 638
#define TT_  24
#define E_   300
#define KP_  320
#define H_   256
#define NG_  2048

DEV uint16_t f2bf(float f) {
    uint32_t u = __float_as_uint(f);
    u += 0x7fffu + ((u >> 16) & 1u);
    return (uint16_t)(u >> 16);
}
DEV float bf2f(uint16_t h) { return __uint_as_float(((uint32_t)h) << 16); }
DEV float sigm(float x)  { return __builtin_amdgcn_rcpf(1.f + __builtin_amdgcn_exp2f(x * -1.4426950408889634f)); }
DEV float tanhx(float x) { return 1.f - 2.f*__builtin_amdgcn_rcpf(1.f + __builtin_amdgcn_exp2f(x * 2.8853900817779268f)); }

DEV void gload_lds16(const void* g, void* l) {
    __builtin_amdgcn_global_load_lds((const __attribute__((address_space(1))) uint32_t*)g,
                                     (__attribute__((address_space(3))) uint32_t*)l, 16, 0, 0);
}

// ---------------- weight prep: wih fp32->bf16 (+K-pad), whh fp32->fp8 -------
__global__ void k_prep(const float* t_wih_f, const float* t_wih_b,
                       const float* t_whh_f,
                       const float* c_wih_f, const float* c_wih_b,
                       const float* c_whh_f, const float* c_whh_b,
                       const float* t_b_f, const float* t_b_b,
                       const float* c_b_f, const float* c_b_b,
                       uint16_t* BwC, uint16_t* BwT, float* biasC, float* biasT,
                       uint32_t* w8CF, uint32_t* w8CB, uint32_t* w8TF)
{
    int tid = blockIdx.x*blockDim.x + threadIdx.x;
    int nth = gridDim.x*blockDim.x;
    for (int i = tid; i < NG_*KP_; i += nth) {
        int n = i / KP_, k = i - n*KP_;
        float vc = 0.f, vt = 0.f;
        if (k < E_) {
            vc = (n < 1024) ? c_wih_f[n*E_+k] : c_wih_b[(n-1024)*E_+k];
            vt = (n < 1024) ? t_wih_f[n*E_+k] : t_wih_b[(n-1024)*E_+k];
        }
        BwC[i] = f2bf(vc); BwT[i] = f2bf(vt);
    }
    for (int i = tid; i < 1024*H_/4; i += nth) {    // fp8 whh (all gates)
        int base = i*4;
        uint32_t a, b, c;
        a = (uint32_t)__builtin_amdgcn_cvt_pk_fp8_f32(c_whh_f[base], c_whh_f[base+1], 0, false);
        a = (uint32_t)__builtin_amdgcn_cvt_pk_fp8_f32(c_whh_f[base+2], c_whh_f[base+3], (int)a, true);
        b = (uint32_t)__builtin_amdgcn_cvt_pk_fp8_f32(c_whh_b[base], c_whh_b[base+1], 0, false);
        b = (uint32_t)__builtin_amdgcn_cvt_pk_fp8_f32(c_whh_b[base+2], c_whh_b[base+3], (int)b, true);
        c = (uint32_t)__builtin_amdgcn_cvt_pk_fp8_f32(t_whh_f[base], t_whh_f[base+1], 0, false);
        c = (uint32_t)__builtin_amdgcn_cvt_pk_fp8_f32(t_whh_f[base+2], t_whh_f[base+3], (int)c, true);
        w8CF[i] = a; w8CB[i] = b; w8TF[i] = c;
    }
    for (int i = tid; i < NG_; i += nth) {
        biasC[i] = (i < 1024) ? c_b_f[i] : c_b_b[i-1024];
        biasT[i] = (i < 1024) ? t_b_f[i] : t_b_b[i-1024];
    }
}

// ---------------- embedding gather -> bf16 A matrices (row m = t*64 + b) ----
__global__ void k_gather(const int* __restrict__ content, const int* __restrict__ title,
                         const float* __restrict__ emb,
                         uint16_t* __restrict__ Ac, uint16_t* __restrict__ At)
{
    int tid = blockIdx.x*blockDim.x + threadIdx.x;
    int nth = gridDim.x*blockDim.x;
    const int CCH = 40832*40;
    const int TCH = 1536*40;
    for (int i = tid; i < CCH + TCH; i += nth) {
        uint16_t* dst; int row, c8; int tok;
        if (i < CCH) {
            row = i / 40; c8 = i - row*40;
            int t = row >> 6, b = row & 63;
            tok = (t < TC_) ? content[b*TC_ + t] : -1;
            dst = Ac + (size_t)row*KP_ + c8*8;
        } else {
            int jx = i - CCH;
            row = jx / 40; c8 = jx - row*40;
            int t = row >> 6, b = row & 63;
            tok = title[b*TT_ + t];
            dst = At + (size_t)row*KP_ + c8*8;
        }
        uint32_t dd[4];
        #pragma unroll
        for (int p = 0; p < 4; ++p) {
            int k = c8*8 + p*2;
            float f0 = (tok >= 0 && k   < E_) ? emb[(size_t)tok*E_ + k]   : 0.f;
            float f1 = (tok >= 0 && k+1 < E_) ? emb[(size_t)tok*E_ + k+1] : 0.f;
            dd[p] = (uint32_t)f2bf(f0) | ((uint32_t)f2bf(f1) << 16);
        }
        uint4 q; q.x = dd[0]; q.y = dd[1]; q.z = dd[2]; q.w = dd[3];
        *(uint4*)dst = q;
    }
}

// ---------------- pre-GEMM: swapped operands: D = W-tile x act^T ------------
// 128x128 tile, BK=32, 4 waves, double-buffered global_load_lds staging.
__global__ __launch_bounds__(256) void k_gemm(const uint16_t* __restrict__ A,
        const uint16_t* __restrict__ Bw, const float* __restrict__ bias,
        uint16_t* __restrict__ prep)
{
    __shared__ __align__(16) uint16_t lA[2][128*32];
    __shared__ __align__(16) uint16_t lB[2][128*32];
    const int tid = threadIdx.x;
    const int l = tid & 63, wv = tid >> 6;
    const int m0 = blockIdx.y * 128, n0 = blockIdx.x * 128;

    auto stage = [&](int kc, int bi) {
        #pragma unroll
        for (int r = 0; r < 2; ++r) {
            int row = r*64 + (tid >> 2);
            int cu  = (tid & 3) * 8;
            gload_lds16(A  + (size_t)(m0 + row)*KP_ + kc*32 + cu, &lA[bi][r*2048 + wv*512]);
            gload_lds16(Bw + (size_t)(n0 + row)*KP_ + kc*32 + cu, &lB[bi][r*2048 + wv*512]);
        }
    };

    f32x4v acc[4][4];
    #pragma unroll
    for (int i = 0; i < 4; ++i)
        #pragma unroll
        for (int j = 0; j < 4; ++j)
            acc[i][j] = f32x4v{0.f,0.f,0.f,0.f};

    const int mtb = (wv >> 1) * 4, ntb = (wv & 1) * 4;

    stage(0, 0);
    __syncthreads();
    for (int kc = 0; kc < 10; ++kc) {
        if (kc < 9) stage(kc + 1, (kc + 1) & 1);
        {
            int bi = kc & 1;
            bf16x8v af[4], bfr[4];
            #pragma unroll
            for (int i = 0; i < 4; ++i) {
                af[i]  = *(const bf16x8v*)&lA[bi][((mtb+i)*16 + (l&15))*32 + (l>>4)*8];
                bfr[i] = *(const bf16x8v*)&lB[bi][((ntb+i)*16 + (l&15))*32 + (l>>4)*8];
            }
            #pragma unroll
            for (int i = 0; i < 4; ++i)
                #pragma unroll
                for (int j = 0; j < 4; ++j)
                    acc[i][j] = __builtin_amdgcn_mfma_f32_16x16x32_bf16(bfr[j], af[i], acc[i][j], 0,0,0);
        }
        __syncthreads();
    }

    // epilogue: D[n_local = hi*4+r][m = l&15]; store ushort4 per (i,j)
    const int hi = l >> 4;
    #pragma unroll
    for (int j = 0; j < 4; ++j) {
        int n16 = (n0 >> 4) + ntb + j;      // col-tile index 0..127
        int dir = n16 >> 6;
        int q   = n16 & 63;
        int ty  = q >> 4;
        int wp  = q & 15;
        float4 bv = *(const float4*)(bias + n16*16 + hi*4);
        #pragma unroll
        for (int i = 0; i < 4; ++i) {
            int rowblk = (m0 >> 4) + mtb + i;   // 16-row block index
            int t    = rowblk >> 2;
            int bblk = rowblk & 3;
            int unit = t*8 + bblk*2 + dir;
            ushort4 pk;
            pk.x = f2bf(acc[i][j][0] + bv.x);
            pk.y = f2bf(acc[i][j][1] + bv.y);
            pk.z = f2bf(acc[i][j][2] + bv.z);
            pk.w = f2bf(acc[i][j][3] + bv.w);
            size_t off = (size_t)unit*16384 + (size_t)wp*1024 + (size_t)l*16 + ty*4;
            *(ushort4*)(prep + off) = pk;
        }
    }
}

// ---------------- recurrence: one block per (direction, 16-batch) unit ------
// 16 waves x 64 lanes; weights in 64 AGPRs (asm-pinned). h: fp8, 2x4KB LDS,
// kc-pair subtiled layout -> 4x ds_read_b128, provably conflict-free.
// Nonlinearity: common-denominator form, 7 transcendentals/output (was 10).
__global__ __launch_bounds__(1024, 4) void k_rnn(
    const uint16_t* __restrict__ preC, const uint16_t* __restrict__ preT,
    const uint8_t* __restrict__ w8CF, const uint8_t* __restrict__ w8CB,
    const uint8_t* __restrict__ w8TF,
    uint16_t* __restrict__ cr, float* __restrict__ tl)
{
    __shared__ __align__(16) char smem[8192];   // 2 x 4KB fp8-h buffers

    const int tid = threadIdx.x;
    const int l = tid & 63, wp = tid >> 6;      // wp 0..15
    const int m = l & 15, hi = l >> 4;
    const int u = blockIdx.x;

    int dir, bblk, t0, tstep, nsteps, tlOff = -1;
    bool doCR = false;
    const uint16_t* pre; const uint8_t* whh8 = nullptr;
    if (u < 8) {
        dir = u & 1; bblk = u >> 1;
        nsteps = TC_; t0 = dir ? (TC_-1) : 0; tstep = dir ? -1 : 1;
        whh8 = dir ? w8CB : w8CF; pre = preC; doCR = true;
    } else if (u < 12) {
        dir = 0; bblk = u - 8; nsteps = TT_; t0 = 0; tstep = 1;
        whh8 = w8TF; pre = preT; tlOff = 0;
    } else {
        dir = 1; bblk = u - 12; nsteps = 1; t0 = TT_-1; tstep = -1;
        whh8 = nullptr; pre = preT; tlOff = 256;
    }
    const int b0 = bblk * 16;

    // ---- weights: 4 fp8 tiles {i,f,g,o} for this wave's 16 h-cols ----------
    i64 w8r[4][8];
    if (whh8) {
        #pragma unroll
        for (int ty = 0; ty < 4; ++ty) {
            int n = ty*256 + wp*16 + m;
            #pragma unroll
            for (int kc = 0; kc < 8; ++kc)
                w8r[ty][kc] = *(const i64*)(whh8 + (size_t)n*H_ + kc*32 + hi*8);
        }
        #pragma unroll
        for (int ty = 0; ty < 4; ++ty)
            #pragma unroll
            for (int kc = 0; kc < 8; ++kc)
                asm volatile("" : "+a"(w8r[ty][kc]));
    }
    for (int i = tid; i < 2048; i += 1024) ((uint32_t*)smem)[i] = 0;
    __syncthreads();

    // ---- per-lane constants ------------------------------------------------
    // read q: addr = m*256 + hi*64 + ((q^(m&3))<<4)  -> b128 = kc 2q, 2q+1
    int rda[4];
    #pragma unroll
    for (int q = 0; q < 4; ++q) rda[q] = m*256 + hi*64 + (((q ^ (m & 3))) << 4);
    // write: j = wp*16 + hi*4 + r; one u32 covering r=0..3
    const int waddr = m*256 + (((wp*2 + (hi >> 1)) & 3) << 6)
                    + ((((wp >> 2) ^ (m & 3))) << 4)
                    + (((wp >> 1) & 1) << 3) + ((hi & 1) << 2);

    uint16_t* crp = cr + ((size_t)(b0 + m)*TC_ + t0)*512 + dir*256 + (wp << 4) + hi*4;
    const intptr_t crAdv = (intptr_t)tstep * 512;

    float cst[4] = {0.f, 0.f, 0.f, 0.f};

    const uint16_t* pp = pre + (size_t)(t0*8 + bblk*2 + dir)*16384
                             + (size_t)(wp << 10) + (size_t)l*16;
    const intptr_t ppAdv = (intptr_t)tstep * 131072;

    uint4 pf0 = *(const uint4*)(pp);
    uint4 pf1 = *(const uint4*)(pp + 8);

    const float KN = -1.4426950408889634f;      // -log2(e)
    const float K2 =  2.8853900817779268f;      //  2 log2(e)

    for (int s = 0; s < nsteps; ++s) {
        const char* hb = (const char*)smem + (s & 1)*4096;
        char*       ho = smem + ((s & 1) ^ 1)*4096;

        // decode pre -> acc (bf16 in hi-half trick)
        f32x4v acc[4];
        acc[0][0]=__uint_as_float(pf0.x<<16); acc[0][1]=__uint_as_float(pf0.x&0xffff0000u);
        acc[0][2]=__uint_as_float(pf0.y<<16); acc[0][3]=__uint_as_float(pf0.y&0xffff0000u);
        acc[1][0]=__uint_as_float(pf0.z<<16); acc[1][1]=__uint_as_float(pf0.z&0xffff0000u);
        acc[1][2]=__uint_as_float(pf0.w<<16); acc[1][3]=__uint_as_float(pf0.w&0xffff0000u);
        acc[2][0]=__uint_as_float(pf1.x<<16); acc[2][1]=__uint_as_float(pf1.x&0xffff0000u);
        acc[2][2]=__uint_as_float(pf1.y<<16); acc[2][3]=__uint_as_float(pf1.y&0xffff0000u);
        acc[3][0]=__uint_as_float(pf1.z<<16); acc[3][1]=__uint_as_float(pf1.z&0xffff0000u);
        acc[3][2]=__uint_as_float(pf1.w<<16); acc[3][3]=__uint_as_float(pf1.w&0xffff0000u);

        if (s + 1 < nsteps) {
            pp += ppAdv;
            pf0 = *(const uint4*)(pp);
            pf1 = *(const uint4*)(pp + 8);
        }

        if (whh8) {
            #pragma unroll
            for (int q = 0; q < 4; ++q) {
                i64x2 a = *(const i64x2*)(hb + rda[q]);
                asm("v_mfma_f32_16x16x32_fp8_fp8 %0, %1, %2, %0"
                    : "+v"(acc[0]) : "a"(w8r[0][2*q]), "v"(a[0]));
                asm("v_mfma_f32_16x16x32_fp8_fp8 %0, %1, %2, %0"
                    : "+v"(acc[1]) : "a"(w8r[1][2*q]), "v"(a[0]));
                asm("v_mfma_f32_16x16x32_fp8_fp8 %0, %1, %2, %0"
                    : "+v"(acc[2]) : "a"(w8r[2][2*q]), "v"(a[0]));
                asm("v_mfma_f32_16x16x32_fp8_fp8 %0, %1, %2, %0"
                    : "+v"(acc[3]) : "a"(w8r[3][2*q]), "v"(a[0]));
                asm("v_mfma_f32_16x16x32_fp8_fp8 %0, %1, %2, %0"
                    : "+v"(acc[0]) : "a"(w8r[0][2*q+1]), "v"(a[1]));
                asm("v_mfma_f32_16x16x32_fp8_fp8 %0, %1, %2, %0"
                    : "+v"(acc[1]) : "a"(w8r[1][2*q+1]), "v"(a[1]));
                asm("v_mfma_f32_16x16x32_fp8_fp8 %0, %1, %2, %0"
                    : "+v"(acc[2]) : "a"(w8r[2][2*q+1]), "v"(a[1]));
                asm("v_mfma_f32_16x16x32_fp8_fp8 %0, %1, %2, %0"
                    : "+v"(acc[3]) : "a"(w8r[3][2*q+1]), "v"(a[1]));
            }
        }

        // nonlinearity: common-denominator form (5 exp + 2 rcp per output)
        float hv[4];
        #pragma unroll
        for (int r = 0; r < 4; ++r) {
            float Ei = __builtin_amdgcn_exp2f(acc[0][r] * KN);
            float Ef = __builtin_amdgcn_exp2f(acc[1][r] * KN);
            float Eg = __builtin_amdgcn_exp2f(acc[2][r] * (2.f*KN));
            float Eo = __builtin_amdgcn_exp2f(acc[3][r] * KN);
            float A  = 1.f + Ei;
            float Bb = 1.f + Eg;
            float C  = 1.f + Ef;
            float AB = A * Bb;
            float num = __builtin_fmaf(cst[r], AB, (2.f - Bb) * C);
            float cv  = num * __builtin_amdgcn_rcpf(AB * C);
            cst[r] = cv;
            float cc = fminf(fmaxf(cv, -15.f), 15.f);
            float P  = __builtin_amdgcn_exp2f(cc * K2);
            hv[r] = (P - 1.f) * __builtin_amdgcn_rcpf((1.f + Eo) * (P + 1.f));
        }

        uint32_t p8 = (uint32_t)__builtin_amdgcn_cvt_pk_fp8_f32(hv[0], hv[1], 0, false);
        p8 = (uint32_t)__builtin_amdgcn_cvt_pk_fp8_f32(hv[2], hv[3], (int)p8, true);
        *(uint32_t*)(ho + waddr) = p8;

        if (doCR) {
            uint32_t b01, b23;
            asm("v_cvt_pk_bf16_f32 %0, %1, %2" : "=v"(b01) : "v"(hv[0]), "v"(hv[1]));
            asm("v_cvt_pk_bf16_f32 %0, %1, %2" : "=v"(b23) : "v"(hv[2]), "v"(hv[3]));
            uint2 st; st.x = b01; st.y = b23;
            *(uint2*)crp = st;
            crp += crAdv;
        }
        if (tlOff >= 0 && s == nsteps - 1) {
            float4 fv; fv.x = hv[0]; fv.y = hv[1]; fv.z = hv[2]; fv.w = hv[3];
            *(float4*)(tl + (size_t)(b0 + m)*512 + tlOff + (wp << 4) + hi*4) = fv;
        }

        // one barrier per step: LDS-only drain; global ops stay in flight
        __builtin_amdgcn_sched_barrier(0);
        asm volatile("s_waitcnt lgkmcnt(0)" ::: "memory");
        __builtin_amdgcn_s_barrier();
        __builtin_amdgcn_sched_barrier(0);
    }
}

// ---------------- attention + fc + log_softmax, one block per batch --------
__global__ __launch_bounds__(256) void k_attn(const uint16_t* __restrict__ cr,
        const float* __restrict__ tl, const float* __restrict__ attw,
        const float* __restrict__ fcw, const float* __restrict__ fcb,
        float* __restrict__ out)
{
    __shared__ float sT[512];
    __shared__ float sQ[512];
    __shared__ float sS[640];
    __shared__ float sR[256];
    const int b = blockIdx.x, tid = threadIdx.x;
    for (int i = tid; i < 512; i += 256) sT[i] = tl[(size_t)b*512 + i];
    __syncthreads();
    for (int n = tid; n < 512; n += 256) {
        float s = 0.f;
        for (int j = 0; j < 512; ++j) s += sT[j] * attw[(size_t)j*512 + n];
        sQ[n] = s;
    }
    __syncthreads();
    for (int t = tid; t < TC_; t += 256) {
        const uint16_t* row = cr + ((size_t)b*TC_ + t)*512;
        float s = 0.f;
        for (int c = 0; c < 64; ++c) {
            uint4 v = *(const uint4*)(row + c*8);
            uint32_t d;
            d = v.x; s += bf2f((uint16_t)(d&0xffff))*sQ[c*8+0] + bf2f((uint16_t)(d>>16))*sQ[c*8+1];
            d = v.y; s += bf2f((uint16_t)(d&0xffff))*sQ[c*8+2] + bf2f((uint16_t)(d>>16))*sQ[c*8+3];
            d = v.z; s += bf2f((uint16_t)(d&0xffff))*sQ[c*8+4] + bf2f((uint16_t)(d>>16))*sQ[c*8+5];
            d = v.w; s += bf2f((uint16_t)(d&0xffff))*sQ[c*8+6] + bf2f((uint16_t)(d>>16))*sQ[c*8+7];
        }
        sS[t] = s;
    }
    __syncthreads();
    float lm = -1e30f;
    for (int t = tid; t < TC_; t += 256) lm = fmaxf(lm, sS[t]);
    sR[tid] = lm; __syncthreads();
    for (int o = 128; o > 0; o >>= 1) { if (tid < o) sR[tid] = fmaxf(sR[tid], sR[tid+o]); __syncthreads(); }
    float M = sR[0]; __syncthreads();
    float ls = 0.f;
    for (int t = tid; t < TC_; t += 256) { float e = __expf(sS[t]-M); sS[t] = e; ls += e; }
    sR[tid] = ls; __syncthreads();
    for (int o = 128; o > 0; o >>= 1) { if (tid < o) sR[tid] += sR[tid+o]; __syncthreads(); }
    float inv = 1.f / sR[0]; __syncthreads();
    float la[5] = {0.f,0.f,0.f,0.f,0.f};
    for (int t = tid; t < TC_; t += 256) {
        float p = sS[t] * inv;
        #pragma unroll
        for (int ll = 0; ll < 5; ++ll) la[ll] += p * fcw[ll*TC_ + t];
    }
    float lg[5];
    #pragma unroll
    for (int ll = 0; ll < 5; ++ll) {
        sR[tid] = la[ll]; __syncthreads();
        for (int o = 128; o > 0; o >>= 1) { if (tid < o) sR[tid] += sR[tid+o]; __syncthreads(); }
        lg[ll] = sR[0] + fcb[ll]; __syncthreads();
    }
    if (tid == 0) {
        float m2 = lg[0];
        #pragma unroll
        for (int ll = 1; ll < 5; ++ll) m2 = fmaxf(m2, lg[ll]);
        float se = 0.f;
        #pragma unroll
        for (int ll = 0; ll < 5; ++ll) se += __expf(lg[ll] - m2);
        float lse = __logf(se) + m2;
        #pragma unroll
        for (int ll = 0; ll < 5; ++ll) out[b*5 + ll] = lg[ll] - lse;
    }
}

// ---------------------------------------------------------------------------
extern "C" void kernel_launch(void* const* d_in, const int* in_sizes, int n_in,
                              void* d_out, int out_size, void* d_ws, size_t ws_size,
                              hipStream_t stream)
{
    const int*   content = (const int*)d_in[0];
    const int*   title   = (const int*)d_in[1];
    const float* embed_w = (const float*)d_in[2];
    const float* t_wih_f = (const float*)d_in[3];
    const float* t_whh_f = (const float*)d_in[4];
    const float* t_b_f   = (const float*)d_in[5];
    const float* t_wih_b = (const float*)d_in[6];
    const float* t_b_b   = (const float*)d_in[8];
    const float* c_wih_f = (const float*)d_in[9];
    const float* c_whh_f = (const float*)d_in[10];
    const float* c_b_f   = (const float*)d_in[11];
    const float* c_wih_b = (const float*)d_in[12];
    const float* c_whh_b = (const float*)d_in[13];
    const float* c_b_b   = (const float*)d_in[14];
    const float* att_w   = (const float*)d_in[15];
    const float* fc_w    = (const float*)d_in[16];
    const float* fc_b    = (const float*)d_in[17];
    float* out = (float*)d_out;

    char* ws = (char*)d_ws;
    size_t o = 0;
    auto alloc = [&](size_t sz) { char* p = ws + o; o = (o + sz + 255) & ~(size_t)255; return p; };
    uint16_t* Ac    = (uint16_t*)alloc((size_t)40832*KP_*2);
    uint16_t* At    = (uint16_t*)alloc((size_t)1536*KP_*2);
    uint16_t* BwC   = (uint16_t*)alloc((size_t)NG_*KP_*2);
    uint16_t* BwT   = (uint16_t*)alloc((size_t)NG_*KP_*2);
    float*    biasC = (float*)   alloc((size_t)NG_*4);
    float*    biasT = (float*)   alloc((size_t)NG_*4);
    uint8_t*  w8CF  = (uint8_t*) alloc((size_t)1024*H_);
    uint8_t*  w8CB  = (uint8_t*) alloc((size_t)1024*H_);
    uint8_t*  w8TF  = (uint8_t*) alloc((size_t)1024*H_);
    uint16_t* preC  = (uint16_t*)alloc((size_t)TCP_*262144);
    uint16_t* preT  = (uint16_t*)alloc((size_t)TT_*262144);
    uint16_t* crp   = (uint16_t*)alloc((size_t)B_*TC_*512*2);
    float*    tlp   = (float*)   alloc((size_t)B_*512*4);

    k_prep<<<256, 256, 0, stream>>>(t_wih_f, t_wih_b, t_whh_f, c_wih_f, c_wih_b,
                                    c_whh_f, c_whh_b, t_b_f, t_b_b, c_b_f, c_b_b,
                                    BwC, BwT, biasC, biasT,
                                    (uint32_t*)w8CF, (uint32_t*)w8CB, (uint32_t*)w8TF);
    k_gather<<<2048, 256, 0, stream>>>(content, title, embed_w, Ac, At);
    k_gemm<<<dim3(16, 319), 256, 0, stream>>>(Ac, BwC, biasC, preC);
    k_gemm<<<dim3(16, 12),  256, 0, stream>>>(At, BwT, biasT, preT);
    k_rnn<<<16, 1024, 0, stream>>>(preC, preT, w8CF, w8CB, w8TF, crp, tlp);
    k_attn<<<64, 256, 0, stream>>>(crp, tlp, att_w, fc_w, fc_b, out);
}